// Round 4
// baseline (519.764 us; speedup 1.0000x reference)
//
#include <hip/hip_runtime.h>
#include <math.h>

#define NN 50000
#define EE 800000
#define RAWD 128
#define HIDD 256
#define OUTD 64
#define KK 4
#define PHID 16

typedef __attribute__((ext_vector_type(8))) short short8;
typedef __attribute__((ext_vector_type(4))) float f32x4;

__device__ inline float b2f(unsigned short u) {
    union { unsigned i; float f; } v; v.i = ((unsigned)u) << 16; return v.f;
}
__device__ inline unsigned short f2b(float f) {
    unsigned u = __float_as_uint(f);
    unsigned r = (u + 0x7FFFu + ((u >> 16) & 1u)) >> 16;   // RNE
    return (unsigned short)r;
}

// ---------------------------------------------------------------------------
// casts
// ---------------------------------------------------------------------------
__global__ void cast_bf16_k(const float* __restrict__ in, unsigned short* __restrict__ out,
                            int count4) {
    int i = blockIdx.x * 256 + threadIdx.x;
    if (i >= count4) return;
    float4 v = ((const float4*)in)[i];
    ushort4 o;
    o.x = f2b(v.x); o.y = f2b(v.y); o.z = f2b(v.z); o.w = f2b(v.w);
    ((ushort4*)out)[i] = o;
}

// Wt[c][r] = W[r][c], rows c >= C are zero-padded (Cpad rows)
__global__ void tcast_k(const float* __restrict__ in, unsigned short* __restrict__ out,
                        int R, int C, int Cpad) {
    int i = blockIdx.x * 256 + threadIdx.x;
    if (i >= R * Cpad) return;
    int c = i / R, r = i % R;
    out[(size_t)c * R + r] = (c < C) ? f2b(in[(size_t)r * C + c]) : (unsigned short)0;
}

// ---------------------------------------------------------------------------
// bf16 MFMA GEMM: C[nrows, BN*gridDim.y] = act(A @ Bt^T + bias)
// BM=128, BK=32, 256 threads (4 waves). Wave grid 2xWN_WAVES, frag grid AMxAN.
// ---------------------------------------------------------------------------
template <int KD, int BN, int WN_WAVES, int AM, int AN, bool RELU, bool OUT_BF16>
__global__ __launch_bounds__(256) void mgemm_k(const unsigned short* __restrict__ A,
                                               const unsigned short* __restrict__ Bt,
                                               const float* __restrict__ bias_vec,
                                               void* __restrict__ Cout,
                                               int nrows, int ldc) {
    const int BM = 128, BK = 32;
    __shared__ __align__(16) unsigned short As[BM * BK];
    __shared__ __align__(16) unsigned short Bs[BN * BK];
    const int tid = threadIdx.x;
    const int w = tid >> 6, l = tid & 63;
    const int row0 = blockIdx.x * BM;
    const int col0 = blockIdx.y * BN;
    const int wr = w / WN_WAVES, wc = w % WN_WAVES;
    const int wm0 = wr * (AM * 16), wn0 = wc * (AN * 16);
    const int l15 = l & 15, l4 = l >> 4;

    const int A_PER = (BM * 4) / 256;          // 2
    const int B_CHUNKS = BN * 4;               // 512 / 256 / 64

    uint4 areg[A_PER];
    uint4 breg[(B_CHUNKS + 255) / 256];

    f32x4 acc[AM][AN];
    #pragma unroll
    for (int m = 0; m < AM; ++m)
        #pragma unroll
        for (int n = 0; n < AN; ++n)
            acc[m][n] = (f32x4){0.f, 0.f, 0.f, 0.f};

    auto loadTiles = [&](int k0) {
        #pragma unroll
        for (int i = 0; i < A_PER; ++i) {
            int idx = i * 256 + tid;
            int r = idx >> 2, c = idx & 3;
            int gr = row0 + r; if (gr >= nrows) gr = nrows - 1;
            areg[i] = *(const uint4*)&A[(size_t)gr * KD + k0 + c * 8];
        }
        if (B_CHUNKS >= 256) {
            #pragma unroll
            for (int i = 0; i < B_CHUNKS / 256; ++i) {
                int idx = i * 256 + tid;
                int r = idx >> 2, c = idx & 3;
                breg[i] = *(const uint4*)&Bt[(size_t)(col0 + r) * KD + k0 + c * 8];
            }
        } else if (tid < B_CHUNKS) {
            int r = tid >> 2, c = tid & 3;
            breg[0] = *(const uint4*)&Bt[(size_t)(col0 + r) * KD + k0 + c * 8];
        }
    };
    auto writeTiles = [&]() {
        #pragma unroll
        for (int i = 0; i < A_PER; ++i) {
            int idx = i * 256 + tid;
            *(uint4*)&As[idx * 8] = areg[i];
        }
        if (B_CHUNKS >= 256) {
            #pragma unroll
            for (int i = 0; i < B_CHUNKS / 256; ++i) {
                int idx = i * 256 + tid;
                *(uint4*)&Bs[idx * 8] = breg[i];
            }
        } else if (tid < B_CHUNKS) {
            *(uint4*)&Bs[tid * 8] = breg[0];
        }
    };

    loadTiles(0);
    const int NT = KD / BK;
    for (int t = 0; t < NT; ++t) {
        __syncthreads();
        writeTiles();
        __syncthreads();
        if (t + 1 < NT) loadTiles((t + 1) * BK);
        short8 af[AM], bfr[AN];
        #pragma unroll
        for (int m = 0; m < AM; ++m)
            af[m] = *(const short8*)&As[(wm0 + m * 16 + l15) * BK + l4 * 8];
        #pragma unroll
        for (int n = 0; n < AN; ++n)
            bfr[n] = *(const short8*)&Bs[(wn0 + n * 16 + l15) * BK + l4 * 8];
        #pragma unroll
        for (int m = 0; m < AM; ++m)
            #pragma unroll
            for (int n = 0; n < AN; ++n)
                acc[m][n] = __builtin_amdgcn_mfma_f32_16x16x32_bf16(af[m], bfr[n], acc[m][n], 0, 0, 0);
    }

    // C/D layout: col=lane&15, row=(lane>>4)*4+reg
    #pragma unroll
    for (int m = 0; m < AM; ++m) {
        #pragma unroll
        for (int n = 0; n < AN; ++n) {
            int gc = col0 + wn0 + n * 16 + l15;
            float bv = bias_vec ? bias_vec[gc] : 0.f;
            #pragma unroll
            for (int r = 0; r < 4; ++r) {
                int gr = row0 + wm0 + m * 16 + l4 * 4 + r;
                if (gr >= nrows) continue;
                float v = acc[m][n][r] + bv;
                if (RELU) v = fmaxf(v, 0.f);
                if (OUT_BF16)
                    ((unsigned short*)Cout)[(size_t)gr * ldc + gc] = f2b(v);
                else
                    ((float*)Cout)[(size_t)gr * ldc + gc] = v;
            }
        }
    }
}

// ---------------------------------------------------------------------------
// tilde_norm + l_sep
// ---------------------------------------------------------------------------
__global__ void tnorm_lsep_k(const float* __restrict__ tilde_phi,
                             float* __restrict__ tnorm,
                             float* __restrict__ lsep_out) {
    __shared__ float tn[KK][PHID];
    int t = threadIdx.x;
    if (t < KK * PHID) {
        float v = tilde_phi[t];
        float sq = v * v;
        #pragma unroll
        for (int s = 8; s; s >>= 1) sq += __shfl_xor(sq, s, 16);
        float tnv = v / sqrtf(sq);
        tn[t >> 4][t & 15] = tnv;
        tnorm[t] = tnv;
    }
    __syncthreads();
    if (t == 0) {
        float tot = 0.f;
        for (int i = 0; i < KK; ++i)
            for (int j = 0; j < KK; ++j) {
                float s2 = 0.f;
                for (int p = 0; p < PHID; ++p) {
                    float df = tn[i][p] - tn[j][p];
                    s2 += df * df;
                }
                tot += s2;
            }
        lsep_out[0] = tot / (float)KK;
    }
}

// ---------------------------------------------------------------------------
__global__ void degree_k(const int* __restrict__ dst, int* __restrict__ deg) {
    int e = blockIdx.x * 256 + threadIdx.x;
    if (e < EE) atomicAdd(&deg[dst[e]], 1);
}

// ---------------------------------------------------------------------------
// device-wide scan over deg[NN], 256 elems/block, 3 dispatches
// ---------------------------------------------------------------------------
#define SCAN_NB ((NN + 255) / 256)   // 196

__global__ __launch_bounds__(256) void scan_partial_k(const int* __restrict__ deg,
                                                      int* __restrict__ bsum) {
    __shared__ int ws_[4];
    int i = blockIdx.x * 256 + threadIdx.x;
    int v = (i < NN) ? deg[i] : 0;
    int x = v;
    #pragma unroll
    for (int s = 32; s; s >>= 1) x += __shfl_xor(x, s);
    if ((threadIdx.x & 63) == 0) ws_[threadIdx.x >> 6] = x;
    __syncthreads();
    if (threadIdx.x == 0) bsum[blockIdx.x] = ws_[0] + ws_[1] + ws_[2] + ws_[3];
}

__global__ __launch_bounds__(256) void scan_bsum_k(int* __restrict__ bsum) {
    __shared__ int sd[256];
    int t = threadIdx.x;
    int v = (t < SCAN_NB) ? bsum[t] : 0;
    sd[t] = v;
    __syncthreads();
    for (int s = 1; s < 256; s <<= 1) {
        int u = (t >= s) ? sd[t - s] : 0;
        __syncthreads();
        sd[t] += u;
        __syncthreads();
    }
    if (t < SCAN_NB) bsum[t] = sd[t] - v;   // exclusive
}

__global__ __launch_bounds__(256) void scan_scatter_k(const int* __restrict__ deg,
                                                      const int* __restrict__ bsum,
                                                      int* __restrict__ offs,
                                                      int* __restrict__ cursor) {
    __shared__ int wexc[4];
    int i = blockIdx.x * 256 + threadIdx.x;
    int lane = threadIdx.x & 63, wid = threadIdx.x >> 6;
    int v = (i < NN) ? deg[i] : 0;
    int x = v;
    #pragma unroll
    for (int d = 1; d < 64; d <<= 1) { int u = __shfl_up(x, d); if (lane >= d) x += u; }
    if (lane == 63) wexc[wid] = x;
    __syncthreads();
    if (threadIdx.x == 0) {
        int a = wexc[0], b = wexc[1], c = wexc[2];
        wexc[0] = 0; wexc[1] = a; wexc[2] = a + b; wexc[3] = a + b + c;
    }
    __syncthreads();
    int excl = (x - v) + wexc[wid] + bsum[blockIdx.x];
    if (i < NN) {
        cursor[i] = excl;
        offs[i + 1] = excl + v;
        if (i == 0) offs[0] = 0;
    }
}

// ---------------------------------------------------------------------------
// edge pass: dist -> normalized -> 4 logits -> exp(w), scatter into CSR slot
// ---------------------------------------------------------------------------
__global__ __launch_bounds__(256) void edge_k(const float* __restrict__ phi,
                                              const float* __restrict__ delta,
                                              const float* __restrict__ tnorm,
                                              const int* __restrict__ src,
                                              const int* __restrict__ dst,
                                              int* __restrict__ cursor,
                                              int* __restrict__ csr_src,
                                              float4* __restrict__ csr_a) {
    __shared__ float tn[KK * PHID];
    if (threadIdx.x < KK * PHID) tn[threadIdx.x] = tnorm[threadIdx.x];
    __syncthreads();
    int e = blockIdx.x * 256 + threadIdx.x;
    if (e >= EE) return;
    int s = src[e], d = dst[e];
    const float4* ps4 = (const float4*)(phi + (size_t)s * 16);
    const float4* pd4 = (const float4*)(phi + (size_t)d * 16);
    float dv[16];
    #pragma unroll
    for (int q = 0; q < 4; ++q) {
        float4 a = ps4[q], b = pd4[q];
        dv[q * 4 + 0] = a.x - b.x;
        dv[q * 4 + 1] = a.y - b.y;
        dv[q * 4 + 2] = a.z - b.z;
        dv[q * 4 + 3] = a.w - b.w;
    }
    bool allz = true;
    float nrm2 = 0.f;
    #pragma unroll
    for (int p = 0; p < 15; ++p) {
        allz = allz && (dv[p] == 0.f);
        nrm2 += dv[p] * dv[p];
    }
    dv[15] = allz ? 1.f : 0.f;
    nrm2 += dv[15];
    float inv = 1.f / fmaxf(sqrtf(nrm2), 1e-8f);
    const float* dl = delta + (size_t)d * 64;
    float res[4];
    #pragma unroll
    for (int k = 0; k < 4; ++k) {
        const float4* dk = (const float4*)(dl + k * 16);
        float sacc = 0.f;
        #pragma unroll
        for (int q = 0; q < 4; ++q) {
            float4 tv = dk[q];
            sacc += dv[q * 4 + 0] * (tn[k * 16 + q * 4 + 0] + tv.x);
            sacc += dv[q * 4 + 1] * (tn[k * 16 + q * 4 + 1] + tv.y);
            sacc += dv[q * 4 + 2] * (tn[k * 16 + q * 4 + 2] + tv.z);
            sacc += dv[q * 4 + 3] * (tn[k * 16 + q * 4 + 3] + tv.w);
        }
        res[k] = sacc * inv;
    }
    int pos = atomicAdd(&cursor[d], 1);
    csr_src[pos] = s;
    // store exp(logit): softmax numerator (logits bounded, no max-sub needed)
    csr_a[pos] = make_float4(__expf(res[0]), __expf(res[1]),
                             __expf(res[2]), __expf(res[3]));
}

// ---------------------------------------------------------------------------
// per-dst single-pass: Sum(w*h) and Sum(w) together, divide at end.
// One block (256 thr) per node: tid = k*64 + ch. Per edge: 1 gather + 1 FMA.
// ---------------------------------------------------------------------------
__global__ __launch_bounds__(256) void aggregate_k(const int* __restrict__ offs,
                                                   const int* __restrict__ csr_src,
                                                   const float* __restrict__ csr_w,
                                                   const unsigned short* __restrict__ h,
                                                   const float* __restrict__ bias,
                                                   float* __restrict__ out) {
    __shared__ float sd[4][64];
    const int n = blockIdx.x;
    const int tid = threadIdx.x;
    const int k = tid >> 6, ch = tid & 63;
    const int beg = offs[n], end = offs[n + 1];

    float acc = 0.f, den = 0.f;
    int p = beg;
    int sn_nx = 0; float w_nx = 0.f;
    if (p < end) { sn_nx = csr_src[p]; w_nx = csr_w[p * 4 + k]; }
    while (p < end) {
        int sn = sn_nx; float w = w_nx;
        int pn = p + 1;
        if (pn < end) { sn_nx = csr_src[pn]; w_nx = csr_w[pn * 4 + k]; }
        den += w;
        acc += w * b2f(h[(size_t)sn * 256 + (k << 6) + ch]);
        p = pn;
    }
    float inv = (den > 0.f) ? 1.f / den : 0.f;
    sd[k][ch] = acc * inv;
    __syncthreads();
    if (k == 0) {
        float v = sd[0][ch] + sd[1][ch] + sd[2][ch] + sd[3][ch] + bias[ch];
        float nr = v * v;
        #pragma unroll
        for (int s = 32; s; s >>= 1) nr += __shfl_xor(nr, s);
        float invn = 1.f / fmaxf(sqrtf(nr), 1e-8f);
        out[(size_t)n * 64 + ch] = v * invn;
    }
}

// ---------------------------------------------------------------------------
__global__ void lfocus_partial_k(const float* __restrict__ delta,
                                 float* __restrict__ part, int count) {
    __shared__ float sd[256];
    float s = 0.f;
    for (int i = blockIdx.x * 256 + threadIdx.x; i < count; i += gridDim.x * 256) {
        float v = delta[i];
        s += v * v;
    }
    sd[threadIdx.x] = s;
    __syncthreads();
    for (int st = 128; st; st >>= 1) {
        if (threadIdx.x < st) sd[threadIdx.x] += sd[threadIdx.x + st];
        __syncthreads();
    }
    if (threadIdx.x == 0) part[blockIdx.x] = sd[0];
}

__global__ void lfocus_final_k(const float* __restrict__ part, int nb,
                               float* __restrict__ outp) {
    __shared__ float sd[256];
    float s = 0.f;
    for (int i = threadIdx.x; i < nb; i += 256) s += part[i];
    sd[threadIdx.x] = s;
    __syncthreads();
    for (int st = 128; st; st >>= 1) {
        if (threadIdx.x < st) sd[threadIdx.x] += sd[threadIdx.x + st];
        __syncthreads();
    }
    if (threadIdx.x == 0) outp[0] = sd[0] / (float)((size_t)NN * KK);
}

// ---------------------------------------------------------------------------
extern "C" void kernel_launch(void* const* d_in, const int* in_sizes, int n_in,
                              void* d_out, int out_size, void* d_ws, size_t ws_size,
                              hipStream_t stream) {
    const float* h_l       = (const float*)d_in[0];
    const float* e_l       = (const float*)d_in[1];
    const int*   src       = (const int*)d_in[2];
    const int*   dst       = (const int*)d_in[3];
    const float* W_phi     = (const float*)d_in[4];
    const float* W1        = (const float*)d_in[5];
    const float* b1        = (const float*)d_in[6];
    const float* W2        = (const float*)d_in[7];
    const float* b2        = (const float*)d_in[8];
    const float* tilde_phi = (const float*)d_in[9];
    const float* W         = (const float*)d_in[10];
    const float* bias      = (const float*)d_in[11];
    float* out = (float*)d_out;

    char* ws = (char*)d_ws;
    size_t off = 0;
    auto alloc = [&](size_t bytes) -> char* {
        char* p = ws + off;
        off += (bytes + 255) & ~(size_t)255;
        return p;
    };
    float*          phi     = (float*)alloc((size_t)NN * 16 * 4);
    float*          delta   = (float*)alloc((size_t)NN * 64 * 4);
    unsigned short* h_bf    = (unsigned short*)alloc((size_t)NN * 256 * 2);
    unsigned short* hid_bf  = (unsigned short*)alloc((size_t)NN * 256 * 2);
    unsigned short* e_bf    = (unsigned short*)alloc((size_t)NN * 128 * 2);
    unsigned short* hl_bf   = (unsigned short*)alloc((size_t)NN * 256 * 2);
    float*          csr_a   = (float*)alloc((size_t)EE * 4 * 4);
    int*            csr_src = (int*)alloc((size_t)EE * 4);
    int*            deg     = (int*)alloc((size_t)NN * 4);
    int*            offs    = (int*)alloc((size_t)(NN + 1) * 4);
    int*            cursor  = (int*)alloc((size_t)NN * 4);
    int*            bsum    = (int*)alloc((size_t)SCAN_NB * 4);
    unsigned short* W_t     = (unsigned short*)alloc(256 * 256 * 2);
    unsigned short* W1_bf   = (unsigned short*)alloc(256 * 128 * 2);
    unsigned short* W2_bf   = (unsigned short*)alloc(64 * 256 * 2);
    unsigned short* Wphi_t  = (unsigned short*)alloc(16 * 128 * 2);
    float*          tnorm   = (float*)alloc(64 * 4);
    float*          part    = (float*)alloc(512 * 4);

    hipMemsetAsync(deg, 0, (size_t)NN * 4, stream);

    tnorm_lsep_k<<<1, 64, 0, stream>>>(tilde_phi, tnorm, out + (size_t)NN * OUTD);

    // casts
    cast_bf16_k<<<(NN * 128 / 4 + 255) / 256, 256, 0, stream>>>(e_l, e_bf, NN * 128 / 4);
    cast_bf16_k<<<(NN * 256 / 4 + 255) / 256, 256, 0, stream>>>(h_l, hl_bf, NN * 256 / 4);
    cast_bf16_k<<<(256 * 128 / 4 + 255) / 256, 256, 0, stream>>>(W1, W1_bf, 256 * 128 / 4);
    cast_bf16_k<<<(64 * 256 / 4 + 255) / 256, 256, 0, stream>>>(W2, W2_bf, 64 * 256 / 4);
    tcast_k<<<(256 * 256 + 255) / 256, 256, 0, stream>>>(W, W_t, 256, 256, 256);
    tcast_k<<<(128 * 16 + 255) / 256, 256, 0, stream>>>(W_phi, Wphi_t, 128, 15, 16);

    const int MB = (NN + 127) / 128;   // 391
    mgemm_k<128, 16, 1, 2, 1, false, false><<<dim3(MB, 1), 256, 0, stream>>>(
        e_bf, Wphi_t, nullptr, phi, NN, 16);
    mgemm_k<128, 128, 2, 4, 4, true, true><<<dim3(MB, 2), 256, 0, stream>>>(
        e_bf, W1_bf, b1, hid_bf, NN, 256);
    mgemm_k<256, 64, 1, 2, 4, false, false><<<dim3(MB, 1), 256, 0, stream>>>(
        hid_bf, W2_bf, b2, delta, NN, 64);
    mgemm_k<256, 128, 2, 4, 4, false, true><<<dim3(MB, 2), 256, 0, stream>>>(
        hl_bf, W_t, nullptr, h_bf, NN, 256);

    // CSR build
    degree_k<<<3125, 256, 0, stream>>>(dst, deg);
    scan_partial_k<<<SCAN_NB, 256, 0, stream>>>(deg, bsum);
    scan_bsum_k<<<1, 256, 0, stream>>>(bsum);
    scan_scatter_k<<<SCAN_NB, 256, 0, stream>>>(deg, bsum, offs, cursor);

    // edge logits -> exp, scatter into CSR
    edge_k<<<3125, 256, 0, stream>>>(phi, delta, tnorm, src, dst, cursor, csr_src,
                                     (float4*)csr_a);

    // per-dst single-pass softmax + aggregation + normalize
    aggregate_k<<<NN, 256, 0, stream>>>(offs, csr_src, csr_a, h_bf, bias, out);

    // l_focus
    lfocus_partial_k<<<512, 256, 0, stream>>>(delta, part, NN * 64);
    lfocus_final_k<<<1, 256, 0, stream>>>(part, 512, out + (size_t)NN * OUTD + 1);
}

// Round 5
// 413.897 us; speedup vs baseline: 1.2558x; 1.2558x over previous
//
#include <hip/hip_runtime.h>
#include <math.h>

#define NN 50000
#define EE 800000
#define RAWD 128
#define HIDD 256
#define OUTD 64
#define KK 4
#define PHID 16

typedef __attribute__((ext_vector_type(8))) short short8;
typedef __attribute__((ext_vector_type(4))) float f32x4;

__device__ inline float b2f(unsigned short u) {
    union { unsigned i; float f; } v; v.i = ((unsigned)u) << 16; return v.f;
}
__device__ inline unsigned short f2b(float f) {
    unsigned u = __float_as_uint(f);
    unsigned r = (u + 0x7FFFu + ((u >> 16) & 1u)) >> 16;   // RNE
    return (unsigned short)r;
}

// ---------------------------------------------------------------------------
// casts
// ---------------------------------------------------------------------------
__global__ void cast_bf16_k(const float* __restrict__ in, unsigned short* __restrict__ out,
                            int count4) {
    int i = blockIdx.x * 256 + threadIdx.x;
    if (i >= count4) return;
    float4 v = ((const float4*)in)[i];
    ushort4 o;
    o.x = f2b(v.x); o.y = f2b(v.y); o.z = f2b(v.z); o.w = f2b(v.w);
    ((ushort4*)out)[i] = o;
}

// Wt[c][r] = W[r][c], rows c >= C are zero-padded (Cpad rows)
__global__ void tcast_k(const float* __restrict__ in, unsigned short* __restrict__ out,
                        int R, int C, int Cpad) {
    int i = blockIdx.x * 256 + threadIdx.x;
    if (i >= R * Cpad) return;
    int c = i / R, r = i % R;
    out[(size_t)c * R + r] = (c < C) ? f2b(in[(size_t)r * C + c]) : (unsigned short)0;
}

// W [256][256], col c = k*64+ch  ->  Wt row c' = ch*4+k  (so h comes out [ch][k])
__global__ void tcast_wperm_k(const float* __restrict__ in, unsigned short* __restrict__ out) {
    int i = blockIdx.x * 256 + threadIdx.x;
    if (i >= 256 * 256) return;
    int c = i >> 8, r = i & 255;
    int k = c >> 6, ch = c & 63;
    int cp = (ch << 2) + k;
    out[(size_t)cp * 256 + r] = f2b(in[(size_t)r * 256 + c]);
}

// ---------------------------------------------------------------------------
// bf16 MFMA GEMM: C[nrows, BN*gridDim.y] = act(A @ Bt^T + bias)
// BM=128, BK=32, 256 threads (4 waves). Wave grid 2xWN_WAVES, frag grid AMxAN.
// ---------------------------------------------------------------------------
template <int KD, int BN, int WN_WAVES, int AM, int AN, bool RELU, bool OUT_BF16>
__global__ __launch_bounds__(256) void mgemm_k(const unsigned short* __restrict__ A,
                                               const unsigned short* __restrict__ Bt,
                                               const float* __restrict__ bias_vec,
                                               void* __restrict__ Cout,
                                               int nrows, int ldc) {
    const int BM = 128, BK = 32;
    __shared__ __align__(16) unsigned short As[BM * BK];
    __shared__ __align__(16) unsigned short Bs[BN * BK];
    const int tid = threadIdx.x;
    const int w = tid >> 6, l = tid & 63;
    const int row0 = blockIdx.x * BM;
    const int col0 = blockIdx.y * BN;
    const int wr = w / WN_WAVES, wc = w % WN_WAVES;
    const int wm0 = wr * (AM * 16), wn0 = wc * (AN * 16);
    const int l15 = l & 15, l4 = l >> 4;

    const int A_PER = (BM * 4) / 256;          // 2
    const int B_CHUNKS = BN * 4;               // 512 / 256 / 64

    uint4 areg[A_PER];
    uint4 breg[(B_CHUNKS + 255) / 256];

    f32x4 acc[AM][AN];
    #pragma unroll
    for (int m = 0; m < AM; ++m)
        #pragma unroll
        for (int n = 0; n < AN; ++n)
            acc[m][n] = (f32x4){0.f, 0.f, 0.f, 0.f};

    auto loadTiles = [&](int k0) {
        #pragma unroll
        for (int i = 0; i < A_PER; ++i) {
            int idx = i * 256 + tid;
            int r = idx >> 2, c = idx & 3;
            int gr = row0 + r; if (gr >= nrows) gr = nrows - 1;
            areg[i] = *(const uint4*)&A[(size_t)gr * KD + k0 + c * 8];
        }
        if (B_CHUNKS >= 256) {
            #pragma unroll
            for (int i = 0; i < B_CHUNKS / 256; ++i) {
                int idx = i * 256 + tid;
                int r = idx >> 2, c = idx & 3;
                breg[i] = *(const uint4*)&Bt[(size_t)(col0 + r) * KD + k0 + c * 8];
            }
        } else if (tid < B_CHUNKS) {
            int r = tid >> 2, c = tid & 3;
            breg[0] = *(const uint4*)&Bt[(size_t)(col0 + r) * KD + k0 + c * 8];
        }
    };
    auto writeTiles = [&]() {
        #pragma unroll
        for (int i = 0; i < A_PER; ++i) {
            int idx = i * 256 + tid;
            *(uint4*)&As[idx * 8] = areg[i];
        }
        if (B_CHUNKS >= 256) {
            #pragma unroll
            for (int i = 0; i < B_CHUNKS / 256; ++i) {
                int idx = i * 256 + tid;
                *(uint4*)&Bs[idx * 8] = breg[i];
            }
        } else if (tid < B_CHUNKS) {
            *(uint4*)&Bs[tid * 8] = breg[0];
        }
    };

    loadTiles(0);
    const int NT = KD / BK;
    for (int t = 0; t < NT; ++t) {
        __syncthreads();
        writeTiles();
        __syncthreads();
        if (t + 1 < NT) loadTiles((t + 1) * BK);
        short8 af[AM], bfr[AN];
        #pragma unroll
        for (int m = 0; m < AM; ++m)
            af[m] = *(const short8*)&As[(wm0 + m * 16 + l15) * BK + l4 * 8];
        #pragma unroll
        for (int n = 0; n < AN; ++n)
            bfr[n] = *(const short8*)&Bs[(wn0 + n * 16 + l15) * BK + l4 * 8];
        #pragma unroll
        for (int m = 0; m < AM; ++m)
            #pragma unroll
            for (int n = 0; n < AN; ++n)
                acc[m][n] = __builtin_amdgcn_mfma_f32_16x16x32_bf16(af[m], bfr[n], acc[m][n], 0, 0, 0);
    }

    // C/D layout: col=lane&15, row=(lane>>4)*4+reg
    #pragma unroll
    for (int m = 0; m < AM; ++m) {
        #pragma unroll
        for (int n = 0; n < AN; ++n) {
            int gc = col0 + wn0 + n * 16 + l15;
            float bv = bias_vec ? bias_vec[gc] : 0.f;
            #pragma unroll
            for (int r = 0; r < 4; ++r) {
                int gr = row0 + wm0 + m * 16 + l4 * 4 + r;
                if (gr >= nrows) continue;
                float v = acc[m][n][r] + bv;
                if (RELU) v = fmaxf(v, 0.f);
                if (OUT_BF16)
                    ((unsigned short*)Cout)[(size_t)gr * ldc + gc] = f2b(v);
                else
                    ((float*)Cout)[(size_t)gr * ldc + gc] = v;
            }
        }
    }
}

// ---------------------------------------------------------------------------
// tilde_norm + l_sep
// ---------------------------------------------------------------------------
__global__ void tnorm_lsep_k(const float* __restrict__ tilde_phi,
                             float* __restrict__ tnorm,
                             float* __restrict__ lsep_out) {
    __shared__ float tn[KK][PHID];
    int t = threadIdx.x;
    if (t < KK * PHID) {
        float v = tilde_phi[t];
        float sq = v * v;
        #pragma unroll
        for (int s = 8; s; s >>= 1) sq += __shfl_xor(sq, s, 16);
        float tnv = v / sqrtf(sq);
        tn[t >> 4][t & 15] = tnv;
        tnorm[t] = tnv;
    }
    __syncthreads();
    if (t == 0) {
        float tot = 0.f;
        for (int i = 0; i < KK; ++i)
            for (int j = 0; j < KK; ++j) {
                float s2 = 0.f;
                for (int p = 0; p < PHID; ++p) {
                    float df = tn[i][p] - tn[j][p];
                    s2 += df * df;
                }
                tot += s2;
            }
        lsep_out[0] = tot / (float)KK;
    }
}

// ---------------------------------------------------------------------------
__global__ void degree_k(const int* __restrict__ dst, int* __restrict__ deg) {
    int e = blockIdx.x * 256 + threadIdx.x;
    if (e < EE) atomicAdd(&deg[dst[e]], 1);
}

// ---------------------------------------------------------------------------
// device-wide scan over deg[NN], 256 elems/block, 3 dispatches
// ---------------------------------------------------------------------------
#define SCAN_NB ((NN + 255) / 256)   // 196

__global__ __launch_bounds__(256) void scan_partial_k(const int* __restrict__ deg,
                                                      int* __restrict__ bsum) {
    __shared__ int ws_[4];
    int i = blockIdx.x * 256 + threadIdx.x;
    int v = (i < NN) ? deg[i] : 0;
    int x = v;
    #pragma unroll
    for (int s = 32; s; s >>= 1) x += __shfl_xor(x, s);
    if ((threadIdx.x & 63) == 0) ws_[threadIdx.x >> 6] = x;
    __syncthreads();
    if (threadIdx.x == 0) bsum[blockIdx.x] = ws_[0] + ws_[1] + ws_[2] + ws_[3];
}

__global__ __launch_bounds__(256) void scan_bsum_k(int* __restrict__ bsum) {
    __shared__ int sd[256];
    int t = threadIdx.x;
    int v = (t < SCAN_NB) ? bsum[t] : 0;
    sd[t] = v;
    __syncthreads();
    for (int s = 1; s < 256; s <<= 1) {
        int u = (t >= s) ? sd[t - s] : 0;
        __syncthreads();
        sd[t] += u;
        __syncthreads();
    }
    if (t < SCAN_NB) bsum[t] = sd[t] - v;   // exclusive
}

__global__ __launch_bounds__(256) void scan_scatter_k(const int* __restrict__ deg,
                                                      const int* __restrict__ bsum,
                                                      int* __restrict__ offs,
                                                      int* __restrict__ cursor) {
    __shared__ int wexc[4];
    int i = blockIdx.x * 256 + threadIdx.x;
    int lane = threadIdx.x & 63, wid = threadIdx.x >> 6;
    int v = (i < NN) ? deg[i] : 0;
    int x = v;
    #pragma unroll
    for (int d = 1; d < 64; d <<= 1) { int u = __shfl_up(x, d); if (lane >= d) x += u; }
    if (lane == 63) wexc[wid] = x;
    __syncthreads();
    if (threadIdx.x == 0) {
        int a = wexc[0], b = wexc[1], c = wexc[2];
        wexc[0] = 0; wexc[1] = a; wexc[2] = a + b; wexc[3] = a + b + c;
    }
    __syncthreads();
    int excl = (x - v) + wexc[wid] + bsum[blockIdx.x];
    if (i < NN) {
        cursor[i] = excl;
        offs[i + 1] = excl + v;
        if (i == 0) offs[0] = 0;
    }
}

// ---------------------------------------------------------------------------
// edge pass: dist -> normalized -> 4 logits -> exp(w), scatter into CSR slot
// ---------------------------------------------------------------------------
__global__ __launch_bounds__(256) void edge_k(const float* __restrict__ phi,
                                              const float* __restrict__ delta,
                                              const float* __restrict__ tnorm,
                                              const int* __restrict__ src,
                                              const int* __restrict__ dst,
                                              int* __restrict__ cursor,
                                              int* __restrict__ csr_src,
                                              float4* __restrict__ csr_a) {
    __shared__ float tn[KK * PHID];
    if (threadIdx.x < KK * PHID) tn[threadIdx.x] = tnorm[threadIdx.x];
    __syncthreads();
    int e = blockIdx.x * 256 + threadIdx.x;
    if (e >= EE) return;
    int s = src[e], d = dst[e];
    const float4* ps4 = (const float4*)(phi + (size_t)s * 16);
    const float4* pd4 = (const float4*)(phi + (size_t)d * 16);
    float dv[16];
    #pragma unroll
    for (int q = 0; q < 4; ++q) {
        float4 a = ps4[q], b = pd4[q];
        dv[q * 4 + 0] = a.x - b.x;
        dv[q * 4 + 1] = a.y - b.y;
        dv[q * 4 + 2] = a.z - b.z;
        dv[q * 4 + 3] = a.w - b.w;
    }
    bool allz = true;
    float nrm2 = 0.f;
    #pragma unroll
    for (int p = 0; p < 15; ++p) {
        allz = allz && (dv[p] == 0.f);
        nrm2 += dv[p] * dv[p];
    }
    dv[15] = allz ? 1.f : 0.f;
    nrm2 += dv[15];
    float inv = 1.f / fmaxf(sqrtf(nrm2), 1e-8f);
    const float* dl = delta + (size_t)d * 64;
    float res[4];
    #pragma unroll
    for (int k = 0; k < 4; ++k) {
        const float4* dk = (const float4*)(dl + k * 16);
        float sacc = 0.f;
        #pragma unroll
        for (int q = 0; q < 4; ++q) {
            float4 tv = dk[q];
            sacc += dv[q * 4 + 0] * (tn[k * 16 + q * 4 + 0] + tv.x);
            sacc += dv[q * 4 + 1] * (tn[k * 16 + q * 4 + 1] + tv.y);
            sacc += dv[q * 4 + 2] * (tn[k * 16 + q * 4 + 2] + tv.z);
            sacc += dv[q * 4 + 3] * (tn[k * 16 + q * 4 + 3] + tv.w);
        }
        res[k] = sacc * inv;
    }
    int pos = atomicAdd(&cursor[d], 1);
    csr_src[pos] = s;
    // store exp(logit): softmax numerator (logits bounded, no max-sub needed)
    csr_a[pos] = make_float4(__expf(res[0]), __expf(res[1]),
                             __expf(res[2]), __expf(res[3]));
}

// ---------------------------------------------------------------------------
// per-dst single-pass aggregation. Wave per node, lane = channel.
// h layout is [node][ch][k] -> one ushort4 gather per lane per edge.
// ---------------------------------------------------------------------------
__global__ __launch_bounds__(256) void aggregate_k(const int* __restrict__ offs,
                                                   const int* __restrict__ csr_src,
                                                   const float4* __restrict__ csr_w,
                                                   const unsigned short* __restrict__ h,
                                                   const float* __restrict__ bias,
                                                   float* __restrict__ out) {
    int wave = threadIdx.x >> 6;
    int lane = threadIdx.x & 63;
    int n = blockIdx.x * 4 + wave;
    if (n >= NN) return;
    int beg = offs[n], end = offs[n + 1];

    float a0 = 0.f, a1 = 0.f, a2 = 0.f, a3 = 0.f;
    float d0 = 0.f, d1 = 0.f, d2 = 0.f, d3 = 0.f;
    int p = beg;
    for (; p + 1 < end; p += 2) {
        float4 wA = csr_w[p];
        float4 wB = csr_w[p + 1];
        int sA = csr_src[p];
        int sB = csr_src[p + 1];
        ushort4 hA = *(const ushort4*)&h[(size_t)sA * 256 + (lane << 2)];
        ushort4 hB = *(const ushort4*)&h[(size_t)sB * 256 + (lane << 2)];
        d0 += wA.x + wB.x; d1 += wA.y + wB.y;
        d2 += wA.z + wB.z; d3 += wA.w + wB.w;
        a0 += wA.x * b2f(hA.x) + wB.x * b2f(hB.x);
        a1 += wA.y * b2f(hA.y) + wB.y * b2f(hB.y);
        a2 += wA.z * b2f(hA.z) + wB.z * b2f(hB.z);
        a3 += wA.w * b2f(hA.w) + wB.w * b2f(hB.w);
    }
    if (p < end) {
        float4 wA = csr_w[p];
        int sA = csr_src[p];
        ushort4 hA = *(const ushort4*)&h[(size_t)sA * 256 + (lane << 2)];
        d0 += wA.x; d1 += wA.y; d2 += wA.z; d3 += wA.w;
        a0 += wA.x * b2f(hA.x);
        a1 += wA.y * b2f(hA.y);
        a2 += wA.z * b2f(hA.z);
        a3 += wA.w * b2f(hA.w);
    }
    float v = (d0 > 0.f ? a0 / d0 : 0.f) + (d1 > 0.f ? a1 / d1 : 0.f) +
              (d2 > 0.f ? a2 / d2 : 0.f) + (d3 > 0.f ? a3 / d3 : 0.f) + bias[lane];
    float nr = v * v;
    #pragma unroll
    for (int s = 32; s; s >>= 1) nr += __shfl_xor(nr, s);
    float invn = 1.f / fmaxf(sqrtf(nr), 1e-8f);
    out[(size_t)n * 64 + lane] = v * invn;
}

// ---------------------------------------------------------------------------
__global__ void lfocus_partial_k(const float* __restrict__ delta,
                                 float* __restrict__ part, int count) {
    __shared__ float sd[256];
    float s = 0.f;
    for (int i = blockIdx.x * 256 + threadIdx.x; i < count; i += gridDim.x * 256) {
        float v = delta[i];
        s += v * v;
    }
    sd[threadIdx.x] = s;
    __syncthreads();
    for (int st = 128; st; st >>= 1) {
        if (threadIdx.x < st) sd[threadIdx.x] += sd[threadIdx.x + st];
        __syncthreads();
    }
    if (threadIdx.x == 0) part[blockIdx.x] = sd[0];
}

__global__ void lfocus_final_k(const float* __restrict__ part, int nb,
                               float* __restrict__ outp) {
    __shared__ float sd[256];
    float s = 0.f;
    for (int i = threadIdx.x; i < nb; i += 256) s += part[i];
    sd[threadIdx.x] = s;
    __syncthreads();
    for (int st = 128; st; st >>= 1) {
        if (threadIdx.x < st) sd[threadIdx.x] += sd[threadIdx.x + st];
        __syncthreads();
    }
    if (threadIdx.x == 0) outp[0] = sd[0] / (float)((size_t)NN * KK);
}

// ---------------------------------------------------------------------------
extern "C" void kernel_launch(void* const* d_in, const int* in_sizes, int n_in,
                              void* d_out, int out_size, void* d_ws, size_t ws_size,
                              hipStream_t stream) {
    const float* h_l       = (const float*)d_in[0];
    const float* e_l       = (const float*)d_in[1];
    const int*   src       = (const int*)d_in[2];
    const int*   dst       = (const int*)d_in[3];
    const float* W_phi     = (const float*)d_in[4];
    const float* W1        = (const float*)d_in[5];
    const float* b1        = (const float*)d_in[6];
    const float* W2        = (const float*)d_in[7];
    const float* b2        = (const float*)d_in[8];
    const float* tilde_phi = (const float*)d_in[9];
    const float* W         = (const float*)d_in[10];
    const float* bias      = (const float*)d_in[11];
    float* out = (float*)d_out;

    char* ws = (char*)d_ws;
    size_t off = 0;
    auto alloc = [&](size_t bytes) -> char* {
        char* p = ws + off;
        off += (bytes + 255) & ~(size_t)255;
        return p;
    };
    float*          phi     = (float*)alloc((size_t)NN * 16 * 4);
    float*          delta   = (float*)alloc((size_t)NN * 64 * 4);
    unsigned short* h_bf    = (unsigned short*)alloc((size_t)NN * 256 * 2);
    unsigned short* hid_bf  = (unsigned short*)alloc((size_t)NN * 256 * 2);
    unsigned short* e_bf    = (unsigned short*)alloc((size_t)NN * 128 * 2);
    unsigned short* hl_bf   = (unsigned short*)alloc((size_t)NN * 256 * 2);
    float*          csr_a   = (float*)alloc((size_t)EE * 4 * 4);
    int*            csr_src = (int*)alloc((size_t)EE * 4);
    int*            deg     = (int*)alloc((size_t)NN * 4);
    int*            offs    = (int*)alloc((size_t)(NN + 1) * 4);
    int*            cursor  = (int*)alloc((size_t)NN * 4);
    int*            bsum    = (int*)alloc((size_t)SCAN_NB * 4);
    unsigned short* W_t     = (unsigned short*)alloc(256 * 256 * 2);
    unsigned short* W1_bf   = (unsigned short*)alloc(256 * 128 * 2);
    unsigned short* W2_bf   = (unsigned short*)alloc(64 * 256 * 2);
    unsigned short* Wphi_t  = (unsigned short*)alloc(16 * 128 * 2);
    float*          tnorm   = (float*)alloc(64 * 4);
    float*          part    = (float*)alloc(512 * 4);

    hipMemsetAsync(deg, 0, (size_t)NN * 4, stream);

    tnorm_lsep_k<<<1, 64, 0, stream>>>(tilde_phi, tnorm, out + (size_t)NN * OUTD);

    // casts
    cast_bf16_k<<<(NN * 128 / 4 + 255) / 256, 256, 0, stream>>>(e_l, e_bf, NN * 128 / 4);
    cast_bf16_k<<<(NN * 256 / 4 + 255) / 256, 256, 0, stream>>>(h_l, hl_bf, NN * 256 / 4);
    cast_bf16_k<<<(256 * 128 / 4 + 255) / 256, 256, 0, stream>>>(W1, W1_bf, 256 * 128 / 4);
    cast_bf16_k<<<(64 * 256 / 4 + 255) / 256, 256, 0, stream>>>(W2, W2_bf, 64 * 256 / 4);
    tcast_wperm_k<<<(256 * 256 + 255) / 256, 256, 0, stream>>>(W, W_t);
    tcast_k<<<(128 * 16 + 255) / 256, 256, 0, stream>>>(W_phi, Wphi_t, 128, 15, 16);

    const int MB = (NN + 127) / 128;   // 391
    mgemm_k<128, 16, 1, 2, 1, false, false><<<dim3(MB, 1), 256, 0, stream>>>(
        e_bf, Wphi_t, nullptr, phi, NN, 16);
    mgemm_k<128, 128, 2, 4, 4, true, true><<<dim3(MB, 2), 256, 0, stream>>>(
        e_bf, W1_bf, b1, hid_bf, NN, 256);
    mgemm_k<256, 64, 1, 2, 4, false, false><<<dim3(MB, 1), 256, 0, stream>>>(
        hid_bf, W2_bf, b2, delta, NN, 64);
    // h (k-interleaved layout [ch][k])
    mgemm_k<256, 128, 2, 4, 4, false, true><<<dim3(MB, 2), 256, 0, stream>>>(
        hl_bf, W_t, nullptr, h_bf, NN, 256);

    // CSR build
    degree_k<<<3125, 256, 0, stream>>>(dst, deg);
    scan_partial_k<<<SCAN_NB, 256, 0, stream>>>(deg, bsum);
    scan_bsum_k<<<1, 256, 0, stream>>>(bsum);
    scan_scatter_k<<<SCAN_NB, 256, 0, stream>>>(deg, bsum, offs, cursor);

    // edge logits -> exp, scatter into CSR
    edge_k<<<3125, 256, 0, stream>>>(phi, delta, tnorm, src, dst, cursor, csr_src,
                                     (float4*)csr_a);

    // per-dst single-pass softmax + aggregation + normalize
    aggregate_k<<<12500, 256, 0, stream>>>(offs, csr_src, (const float4*)csr_a, h_bf,
                                           bias, out);

    // l_focus
    lfocus_partial_k<<<512, 256, 0, stream>>>(delta, part, NN * 64);
    lfocus_final_k<<<1, 256, 0, stream>>>(part, 512, out + (size_t)NN * OUTD + 1);
}

// Round 6
// 335.451 us; speedup vs baseline: 1.5495x; 1.2339x over previous
//
#include <hip/hip_runtime.h>
#include <math.h>

#define NN 50000
#define EE 800000
#define RAWD 128
#define HIDD 256
#define OUTD 64
#define KK 4
#define PHID 16

typedef __attribute__((ext_vector_type(8))) short short8;
typedef __attribute__((ext_vector_type(4))) float f32x4;

__device__ inline float b2f(unsigned short u) {
    union { unsigned i; float f; } v; v.i = ((unsigned)u) << 16; return v.f;
}
__device__ inline unsigned short f2b(float f) {
    unsigned u = __float_as_uint(f);
    unsigned r = (u + 0x7FFFu + ((u >> 16) & 1u)) >> 16;   // RNE
    return (unsigned short)r;
}

// 16-lane (DPP row) all-reduce sum: quad_perm xor1, xor2, then row_ror 4, 8.
__device__ inline float dpp_sum16(float v) {
    int x;
    x = __builtin_amdgcn_update_dpp(0, __float_as_int(v), 0xB1, 0xF, 0xF, true);
    v += __int_as_float(x);
    x = __builtin_amdgcn_update_dpp(0, __float_as_int(v), 0x4E, 0xF, 0xF, true);
    v += __int_as_float(x);
    x = __builtin_amdgcn_update_dpp(0, __float_as_int(v), 0x124, 0xF, 0xF, true);
    v += __int_as_float(x);
    x = __builtin_amdgcn_update_dpp(0, __float_as_int(v), 0x128, 0xF, 0xF, true);
    v += __int_as_float(x);
    return v;
}
__device__ inline float readlane_f(float v, int l) {
    return __int_as_float(__builtin_amdgcn_readlane(__float_as_int(v), l));
}

// ---------------------------------------------------------------------------
// fused weight prep: W_t (perm for [ch][k] h layout), W1, W2, Wphi_t (+pad),
// and zero the l_focus accumulator.
// ---------------------------------------------------------------------------
__global__ void wprep_k(const float* __restrict__ W, const float* __restrict__ W1,
                        const float* __restrict__ W2, const float* __restrict__ W_phi,
                        unsigned short* __restrict__ W_t, unsigned short* __restrict__ W1_bf,
                        unsigned short* __restrict__ W2_bf, unsigned short* __restrict__ Wphi_t,
                        float* __restrict__ lfocus_zero) {
    int i = blockIdx.x * 256 + threadIdx.x;
    if (i == 0) *lfocus_zero = 0.f;
    if (i < 65536) {
        int cp = i >> 8, r = i & 255;
        int ch = cp >> 2, k = cp & 3;
        W_t[i] = f2b(W[(size_t)r * 256 + (k << 6) + ch]);
    } else if (i < 65536 + 32768) {
        int j = i - 65536;
        W1_bf[j] = f2b(W1[j]);
    } else if (i < 65536 + 32768 + 16384) {
        int j = i - 98304;
        W2_bf[j] = f2b(W2[j]);
    } else if (i < 65536 + 32768 + 16384 + 2048) {
        int j = i - 114688;            // j = cp*128 + r
        int cp = j >> 7, r = j & 127;
        Wphi_t[j] = (cp < 15) ? f2b(W_phi[(size_t)r * 15 + cp]) : (unsigned short)0;
    }
}

// ---------------------------------------------------------------------------
// bf16 MFMA GEMM: C[nrows, BN*gridDim.y] = act(A @ Bt^T + bias)
// A: f32 (AF32) or bf16, row-major [nrows][KD]. Bt: bf16 [Ncols][KD].
// BM=128, BK=32, 256 threads (4 waves). LFOCUS: atomic-add sum(v^2)/(N*K).
// ---------------------------------------------------------------------------
template <int KD, int BN, int WN_WAVES, int AM, int AN, bool RELU, bool OUT_BF16,
          bool AF32, bool LFOCUS>
__global__ __launch_bounds__(256) void mgemm_k(const void* __restrict__ A,
                                               const unsigned short* __restrict__ Bt,
                                               const float* __restrict__ bias_vec,
                                               void* __restrict__ Cout,
                                               int nrows, int ldc,
                                               float* __restrict__ lfocus_acc) {
    const int BM = 128, BK = 32;
    __shared__ __align__(16) unsigned short As[BM * BK];
    __shared__ __align__(16) unsigned short Bs[BN * BK];
    const int tid = threadIdx.x;
    const int w = tid >> 6, l = tid & 63;
    const int row0 = blockIdx.x * BM;
    const int col0 = blockIdx.y * BN;
    const int wr = w / WN_WAVES, wc = w % WN_WAVES;
    const int wm0 = wr * (AM * 16), wn0 = wc * (AN * 16);
    const int l15 = l & 15, l4 = l >> 4;

    const int A_PER = (BM * 4) / 256;          // 2
    const int B_CHUNKS = BN * 4;

    uint4 areg[A_PER];
    uint4 breg[(B_CHUNKS + 255) / 256];

    f32x4 acc[AM][AN];
    #pragma unroll
    for (int m = 0; m < AM; ++m)
        #pragma unroll
        for (int n = 0; n < AN; ++n)
            acc[m][n] = (f32x4){0.f, 0.f, 0.f, 0.f};

    auto loadTiles = [&](int k0) {
        #pragma unroll
        for (int i = 0; i < A_PER; ++i) {
            int idx = i * 256 + tid;
            int r = idx >> 2, c = idx & 3;
            int gr = row0 + r; if (gr >= nrows) gr = nrows - 1;
            if (AF32) {
                const float* Af = (const float*)A + (size_t)gr * KD + k0 + c * 8;
                float4 f0 = *(const float4*)Af;
                float4 f1 = *(const float4*)(Af + 4);
                unsigned u0 = f2b(f0.x) | ((unsigned)f2b(f0.y) << 16);
                unsigned u1 = f2b(f0.z) | ((unsigned)f2b(f0.w) << 16);
                unsigned u2 = f2b(f1.x) | ((unsigned)f2b(f1.y) << 16);
                unsigned u3 = f2b(f1.z) | ((unsigned)f2b(f1.w) << 16);
                areg[i] = make_uint4(u0, u1, u2, u3);
            } else {
                areg[i] = *(const uint4*)&((const unsigned short*)A)[(size_t)gr * KD + k0 + c * 8];
            }
        }
        if (B_CHUNKS >= 256) {
            #pragma unroll
            for (int i = 0; i < B_CHUNKS / 256; ++i) {
                int idx = i * 256 + tid;
                int r = idx >> 2, c = idx & 3;
                breg[i] = *(const uint4*)&Bt[(size_t)(col0 + r) * KD + k0 + c * 8];
            }
        } else if (tid < B_CHUNKS) {
            int r = tid >> 2, c = tid & 3;
            breg[0] = *(const uint4*)&Bt[(size_t)(col0 + r) * KD + k0 + c * 8];
        }
    };
    auto writeTiles = [&]() {
        #pragma unroll
        for (int i = 0; i < A_PER; ++i) {
            int idx = i * 256 + tid;
            *(uint4*)&As[idx * 8] = areg[i];
        }
        if (B_CHUNKS >= 256) {
            #pragma unroll
            for (int i = 0; i < B_CHUNKS / 256; ++i) {
                int idx = i * 256 + tid;
                *(uint4*)&Bs[idx * 8] = breg[i];
            }
        } else if (tid < B_CHUNKS) {
            *(uint4*)&Bs[tid * 8] = breg[0];
        }
    };

    loadTiles(0);
    const int NT = KD / BK;
    for (int t = 0; t < NT; ++t) {
        __syncthreads();
        writeTiles();
        __syncthreads();
        if (t + 1 < NT) loadTiles((t + 1) * BK);
        short8 af[AM], bfr[AN];
        #pragma unroll
        for (int m = 0; m < AM; ++m)
            af[m] = *(const short8*)&As[(wm0 + m * 16 + l15) * BK + l4 * 8];
        #pragma unroll
        for (int n = 0; n < AN; ++n)
            bfr[n] = *(const short8*)&Bs[(wn0 + n * 16 + l15) * BK + l4 * 8];
        #pragma unroll
        for (int m = 0; m < AM; ++m)
            #pragma unroll
            for (int n = 0; n < AN; ++n)
                acc[m][n] = __builtin_amdgcn_mfma_f32_16x16x32_bf16(af[m], bfr[n], acc[m][n], 0, 0, 0);
    }

    float lf = 0.f;
    // C/D layout: col=lane&15, row=(lane>>4)*4+reg
    #pragma unroll
    for (int m = 0; m < AM; ++m) {
        #pragma unroll
        for (int n = 0; n < AN; ++n) {
            int gc = col0 + wn0 + n * 16 + l15;
            float bv = bias_vec ? bias_vec[gc] : 0.f;
            #pragma unroll
            for (int r = 0; r < 4; ++r) {
                int gr = row0 + wm0 + m * 16 + l4 * 4 + r;
                if (gr >= nrows) continue;
                float v = acc[m][n][r] + bv;
                if (RELU) v = fmaxf(v, 0.f);
                if (LFOCUS) lf += v * v;
                if (OUT_BF16)
                    ((unsigned short*)Cout)[(size_t)gr * ldc + gc] = f2b(v);
                else
                    ((float*)Cout)[(size_t)gr * ldc + gc] = v;
            }
        }
    }
    if (LFOCUS) {
        #pragma unroll
        for (int s = 32; s; s >>= 1) lf += __shfl_xor(lf, s);
        if ((tid & 63) == 0)
            atomicAdd(lfocus_acc, lf * (1.f / ((float)NN * KK)));
    }
}

// ---------------------------------------------------------------------------
// tilde_norm + l_sep
// ---------------------------------------------------------------------------
__global__ void tnorm_lsep_k(const float* __restrict__ tilde_phi,
                             float* __restrict__ tnorm,
                             float* __restrict__ lsep_out) {
    __shared__ float tn[KK][PHID];
    int t = threadIdx.x;
    if (t < KK * PHID) {
        float v = tilde_phi[t];
        float sq = v * v;
        #pragma unroll
        for (int s = 8; s; s >>= 1) sq += __shfl_xor(sq, s, 16);
        float tnv = v / sqrtf(sq);
        tn[t >> 4][t & 15] = tnv;
        tnorm[t] = tnv;
    }
    __syncthreads();
    if (t == 0) {
        float tot = 0.f;
        for (int i = 0; i < KK; ++i)
            for (int j = 0; j < KK; ++j) {
                float s2 = 0.f;
                for (int p = 0; p < PHID; ++p) {
                    float df = tn[i][p] - tn[j][p];
                    s2 += df * df;
                }
                tot += s2;
            }
        lsep_out[0] = tot / (float)KK;
    }
}

// ---------------------------------------------------------------------------
__global__ void degree_k(const int* __restrict__ dst, int* __restrict__ deg) {
    int e = blockIdx.x * 256 + threadIdx.x;
    if (e < EE) atomicAdd(&deg[dst[e]], 1);
}

// ---------------------------------------------------------------------------
// device-wide scan over deg[NN]
// ---------------------------------------------------------------------------
#define SCAN_NB ((NN + 255) / 256)   // 196

__global__ __launch_bounds__(256) void scan_partial_k(const int* __restrict__ deg,
                                                      int* __restrict__ bsum) {
    __shared__ int ws_[4];
    int i = blockIdx.x * 256 + threadIdx.x;
    int v = (i < NN) ? deg[i] : 0;
    int x = v;
    #pragma unroll
    for (int s = 32; s; s >>= 1) x += __shfl_xor(x, s);
    if ((threadIdx.x & 63) == 0) ws_[threadIdx.x >> 6] = x;
    __syncthreads();
    if (threadIdx.x == 0) bsum[blockIdx.x] = ws_[0] + ws_[1] + ws_[2] + ws_[3];
}

__global__ __launch_bounds__(256) void scan_bsum_k(int* __restrict__ bsum) {
    __shared__ int sd[256];
    int t = threadIdx.x;
    int v = (t < SCAN_NB) ? bsum[t] : 0;
    sd[t] = v;
    __syncthreads();
    for (int s = 1; s < 256; s <<= 1) {
        int u = (t >= s) ? sd[t - s] : 0;
        __syncthreads();
        sd[t] += u;
        __syncthreads();
    }
    if (t < SCAN_NB) bsum[t] = sd[t] - v;   // exclusive
}

__global__ __launch_bounds__(256) void scan_scatter_k(const int* __restrict__ deg,
                                                      const int* __restrict__ bsum,
                                                      int* __restrict__ offs,
                                                      int* __restrict__ cursor) {
    __shared__ int wexc[4];
    int i = blockIdx.x * 256 + threadIdx.x;
    int lane = threadIdx.x & 63, wid = threadIdx.x >> 6;
    int v = (i < NN) ? deg[i] : 0;
    int x = v;
    #pragma unroll
    for (int d = 1; d < 64; d <<= 1) { int u = __shfl_up(x, d); if (lane >= d) x += u; }
    if (lane == 63) wexc[wid] = x;
    __syncthreads();
    if (threadIdx.x == 0) {
        int a = wexc[0], b = wexc[1], c = wexc[2];
        wexc[0] = 0; wexc[1] = a; wexc[2] = a + b; wexc[3] = a + b + c;
    }
    __syncthreads();
    int excl = (x - v) + wexc[wid] + bsum[blockIdx.x];
    if (i < NN) {
        cursor[i] = excl;
        offs[i + 1] = excl + v;
        if (i == 0) offs[0] = 0;
    }
}

// ---------------------------------------------------------------------------
// CSR src scatter (4 B per edge)
// ---------------------------------------------------------------------------
__global__ void scatter_src_k(const int* __restrict__ src, const int* __restrict__ dst,
                              int* __restrict__ cursor, int* __restrict__ csr_src) {
    int e = blockIdx.x * 256 + threadIdx.x;
    if (e >= EE) return;
    int pos = atomicAdd(&cursor[dst[e]], 1);
    csr_src[pos] = src[e];
}

// ---------------------------------------------------------------------------
// Fused per-dst edge compute + softmax + aggregation + normalize.
// Wave per node. Lane l = (k=l>>4 group, p=l&15 phi-dim) for edge math,
// and l = channel for aggregation (h layout [node][ch][k] -> ushort4/lane).
// ---------------------------------------------------------------------------
__global__ __launch_bounds__(256) void edge_agg_k(const int* __restrict__ offs,
                                                  const int* __restrict__ csr_src,
                                                  const float* __restrict__ phi,
                                                  const float* __restrict__ delta,
                                                  const float* __restrict__ tnorm,
                                                  const unsigned short* __restrict__ h,
                                                  const float* __restrict__ bias,
                                                  float* __restrict__ out) {
    const int wave = threadIdx.x >> 6, lane = threadIdx.x & 63;
    const int n = blockIdx.x * 4 + wave;
    if (n >= NN) return;
    const int lp = lane & 15;
    const float phid = phi[(size_t)n * 16 + lp];
    const float tdl = tnorm[lane] + delta[(size_t)n * 64 + lane];
    const int beg = offs[n], end = offs[n + 1];

    float acc0 = 0.f, acc1 = 0.f, acc2 = 0.f, acc3 = 0.f;
    float den0 = 0.f, den1 = 0.f, den2 = 0.f, den3 = 0.f;

    int s_cur = 0, s_nxt = 0;
    float ph_cur = 0.f;
    ushort4 h_cur = make_ushort4(0, 0, 0, 0);
    if (beg < end) {
        s_cur = csr_src[beg];
        s_nxt = (beg + 1 < end) ? csr_src[beg + 1] : s_cur;
        ph_cur = phi[(size_t)s_cur * 16 + lp];
        h_cur = *(const ushort4*)&h[(size_t)s_cur * 256 + (lane << 2)];
    }
    for (int p = beg; p < end; ++p) {
        // prefetch next edge's data (address ready), and src index 2 ahead
        float ph_n = phi[(size_t)s_nxt * 16 + lp];
        ushort4 h_n = *(const ushort4*)&h[(size_t)s_nxt * 256 + (lane << 2)];
        int s_n2 = (p + 2 < end) ? csr_src[p + 2] : 0;

        // dist (lane15 component starts at 0: phi col15 is 0)
        float dv = ph_cur - phid;
        float nr = dpp_sum16(dv * dv);            // sum over 15 real dims
        float z = (nr == 0.f) ? 1.f : 0.f;        // coincident-edge mask
        if (lp == 15) dv = z;
        float inv = 1.f / fmaxf(sqrtf(nr + z), 1e-8f);
        float a = dpp_sum16(dv * tdl) * inv;      // logit for this lane's k-group
        float w = __expf(a);
        float w0 = readlane_f(w, 0), w1 = readlane_f(w, 16);
        float w2 = readlane_f(w, 32), w3 = readlane_f(w, 48);
        den0 += w0; den1 += w1; den2 += w2; den3 += w3;
        acc0 += w0 * b2f(h_cur.x);
        acc1 += w1 * b2f(h_cur.y);
        acc2 += w2 * b2f(h_cur.z);
        acc3 += w3 * b2f(h_cur.w);

        s_cur = s_nxt; ph_cur = ph_n; h_cur = h_n; s_nxt = s_n2;
    }
    float v = (den0 > 0.f ? acc0 / den0 : 0.f) + (den1 > 0.f ? acc1 / den1 : 0.f) +
              (den2 > 0.f ? acc2 / den2 : 0.f) + (den3 > 0.f ? acc3 / den3 : 0.f) +
              bias[lane];
    float nrm = v * v;
    #pragma unroll
    for (int s = 32; s; s >>= 1) nrm += __shfl_xor(nrm, s);
    out[(size_t)n * 64 + lane] = v / fmaxf(sqrtf(nrm), 1e-8f);
}

// ---------------------------------------------------------------------------
extern "C" void kernel_launch(void* const* d_in, const int* in_sizes, int n_in,
                              void* d_out, int out_size, void* d_ws, size_t ws_size,
                              hipStream_t stream) {
    const float* h_l       = (const float*)d_in[0];
    const float* e_l       = (const float*)d_in[1];
    const int*   src       = (const int*)d_in[2];
    const int*   dst       = (const int*)d_in[3];
    const float* W_phi     = (const float*)d_in[4];
    const float* W1        = (const float*)d_in[5];
    const float* b1        = (const float*)d_in[6];
    const float* W2        = (const float*)d_in[7];
    const float* b2        = (const float*)d_in[8];
    const float* tilde_phi = (const float*)d_in[9];
    const float* W         = (const float*)d_in[10];
    const float* bias      = (const float*)d_in[11];
    float* out = (float*)d_out;
    float* lsep_ptr   = out + (size_t)NN * OUTD;
    float* lfocus_ptr = out + (size_t)NN * OUTD + 1;

    char* ws = (char*)d_ws;
    size_t off = 0;
    auto alloc = [&](size_t bytes) -> char* {
        char* p = ws + off;
        off += (bytes + 255) & ~(size_t)255;
        return p;
    };
    float*          phi     = (float*)alloc((size_t)NN * 16 * 4);
    float*          delta   = (float*)alloc((size_t)NN * 64 * 4);
    unsigned short* h_bf    = (unsigned short*)alloc((size_t)NN * 256 * 2);
    unsigned short* hid_bf  = (unsigned short*)alloc((size_t)NN * 256 * 2);
    int*            csr_src = (int*)alloc((size_t)EE * 4);
    int*            deg     = (int*)alloc((size_t)NN * 4);
    int*            offs    = (int*)alloc((size_t)(NN + 1) * 4);
    int*            cursor  = (int*)alloc((size_t)NN * 4);
    int*            bsum    = (int*)alloc((size_t)SCAN_NB * 4);
    unsigned short* W_t     = (unsigned short*)alloc(256 * 256 * 2);
    unsigned short* W1_bf   = (unsigned short*)alloc(256 * 128 * 2);
    unsigned short* W2_bf   = (unsigned short*)alloc(64 * 256 * 2);
    unsigned short* Wphi_t  = (unsigned short*)alloc(16 * 128 * 2);
    float*          tnorm   = (float*)alloc(64 * 4);

    hipMemsetAsync(deg, 0, (size_t)NN * 4, stream);

    tnorm_lsep_k<<<1, 64, 0, stream>>>(tilde_phi, tnorm, lsep_ptr);
    wprep_k<<<(116736 + 255) / 256, 256, 0, stream>>>(W, W1, W2, W_phi, W_t, W1_bf,
                                                      W2_bf, Wphi_t, lfocus_ptr);

    const int MB = (NN + 127) / 128;   // 391
    // phi = e_l @ W_phi (padded to 16 cols)
    mgemm_k<128, 16, 1, 2, 1, false, false, true, false>
        <<<dim3(MB, 1), 256, 0, stream>>>(e_l, Wphi_t, nullptr, phi, NN, 16, nullptr);
    // hid = relu(e_l @ W1^T + b1) -> bf16
    mgemm_k<128, 128, 2, 4, 4, true, true, true, false>
        <<<dim3(MB, 2), 256, 0, stream>>>(e_l, W1_bf, b1, hid_bf, NN, 256, nullptr);
    // delta = hid @ W2^T + b2 -> f32, fused l_focus
    mgemm_k<256, 64, 1, 2, 4, false, false, false, true>
        <<<dim3(MB, 1), 256, 0, stream>>>(hid_bf, W2_bf, b2, delta, NN, 64, lfocus_ptr);
    // h = h_l @ W -> bf16, [ch][k]-interleaved layout
    mgemm_k<256, 128, 2, 4, 4, false, true, true, false>
        <<<dim3(MB, 2), 256, 0, stream>>>(h_l, W_t, nullptr, h_bf, NN, 256, nullptr);

    // CSR build
    degree_k<<<3125, 256, 0, stream>>>(dst, deg);
    scan_partial_k<<<SCAN_NB, 256, 0, stream>>>(deg, bsum);
    scan_bsum_k<<<1, 256, 0, stream>>>(bsum);
    scan_scatter_k<<<SCAN_NB, 256, 0, stream>>>(deg, bsum, offs, cursor);
    scatter_src_k<<<3125, 256, 0, stream>>>(src, dst, cursor, csr_src);

    // fused edge logits + softmax + aggregation + row-normalize
    edge_agg_k<<<12500, 256, 0, stream>>>(offs, csr_src, phi, delta, tnorm, h_bf,
                                          bias, out);
}

// Round 7
// 325.542 us; speedup vs baseline: 1.5966x; 1.0304x over previous
//
#include <hip/hip_runtime.h>
#include <math.h>

#define NN 50000
#define EE 800000
#define RAWD 128
#define HIDD 256
#define OUTD 64
#define KK 4
#define PHID 16

typedef __attribute__((ext_vector_type(8))) short short8;
typedef __attribute__((ext_vector_type(4))) float f32x4;

__device__ inline float b2f(unsigned short u) {
    union { unsigned i; float f; } v; v.i = ((unsigned)u) << 16; return v.f;
}
__device__ inline unsigned short f2b(float f) {
    unsigned u = __float_as_uint(f);
    unsigned r = (u + 0x7FFFu + ((u >> 16) & 1u)) >> 16;   // RNE
    return (unsigned short)r;
}

// ---------------------------------------------------------------------------
// fused weight prep: W_t (perm for [ch][k] h layout), W1, W2, Wphi_t (+pad),
// and zero the l_focus accumulator.
// ---------------------------------------------------------------------------
__global__ void wprep_k(const float* __restrict__ W, const float* __restrict__ W1,
                        const float* __restrict__ W2, const float* __restrict__ W_phi,
                        unsigned short* __restrict__ W_t, unsigned short* __restrict__ W1_bf,
                        unsigned short* __restrict__ W2_bf, unsigned short* __restrict__ Wphi_t,
                        float* __restrict__ lfocus_zero) {
    int i = blockIdx.x * 256 + threadIdx.x;
    if (i == 0) *lfocus_zero = 0.f;
    if (i < 65536) {
        int cp = i >> 8, r = i & 255;
        int ch = cp >> 2, k = cp & 3;
        W_t[i] = f2b(W[(size_t)r * 256 + (k << 6) + ch]);
    } else if (i < 65536 + 32768) {
        int j = i - 65536;
        W1_bf[j] = f2b(W1[j]);
    } else if (i < 65536 + 32768 + 16384) {
        int j = i - 98304;
        W2_bf[j] = f2b(W2[j]);
    } else if (i < 65536 + 32768 + 16384 + 2048) {
        int j = i - 114688;            // j = cp*128 + r
        int cp = j >> 7, r = j & 127;
        Wphi_t[j] = (cp < 15) ? f2b(W_phi[(size_t)r * 15 + cp]) : (unsigned short)0;
    }
}

// ---------------------------------------------------------------------------
// bf16 MFMA GEMM: C[nrows, BN*gridDim.y] = act(A @ Bt^T + bias)
// A: f32 (AF32) or bf16, row-major [nrows][KD]. Bt: bf16 [Ncols][KD].
// BM=128, BK=32, 256 threads (4 waves). LFOCUS: atomic-add sum(v^2)/(N*K).
// ---------------------------------------------------------------------------
template <int KD, int BN, int WN_WAVES, int AM, int AN, bool RELU, bool OUT_BF16,
          bool AF32, bool LFOCUS>
__global__ __launch_bounds__(256) void mgemm_k(const void* __restrict__ A,
                                               const unsigned short* __restrict__ Bt,
                                               const float* __restrict__ bias_vec,
                                               void* __restrict__ Cout,
                                               int nrows, int ldc,
                                               float* __restrict__ lfocus_acc) {
    const int BM = 128, BK = 32;
    __shared__ __align__(16) unsigned short As[BM * BK];
    __shared__ __align__(16) unsigned short Bs[BN * BK];
    const int tid = threadIdx.x;
    const int w = tid >> 6, l = tid & 63;
    const int row0 = blockIdx.x * BM;
    const int col0 = blockIdx.y * BN;
    const int wr = w / WN_WAVES, wc = w % WN_WAVES;
    const int wm0 = wr * (AM * 16), wn0 = wc * (AN * 16);
    const int l15 = l & 15, l4 = l >> 4;

    const int A_PER = (BM * 4) / 256;          // 2
    const int B_CHUNKS = BN * 4;

    uint4 areg[A_PER];
    uint4 breg[(B_CHUNKS + 255) / 256];

    f32x4 acc[AM][AN];
    #pragma unroll
    for (int m = 0; m < AM; ++m)
        #pragma unroll
        for (int n = 0; n < AN; ++n)
            acc[m][n] = (f32x4){0.f, 0.f, 0.f, 0.f};

    auto loadTiles = [&](int k0) {
        #pragma unroll
        for (int i = 0; i < A_PER; ++i) {
            int idx = i * 256 + tid;
            int r = idx >> 2, c = idx & 3;
            int gr = row0 + r; if (gr >= nrows) gr = nrows - 1;
            if (AF32) {
                const float* Af = (const float*)A + (size_t)gr * KD + k0 + c * 8;
                float4 f0 = *(const float4*)Af;
                float4 f1 = *(const float4*)(Af + 4);
                unsigned u0 = f2b(f0.x) | ((unsigned)f2b(f0.y) << 16);
                unsigned u1 = f2b(f0.z) | ((unsigned)f2b(f0.w) << 16);
                unsigned u2 = f2b(f1.x) | ((unsigned)f2b(f1.y) << 16);
                unsigned u3 = f2b(f1.z) | ((unsigned)f2b(f1.w) << 16);
                areg[i] = make_uint4(u0, u1, u2, u3);
            } else {
                areg[i] = *(const uint4*)&((const unsigned short*)A)[(size_t)gr * KD + k0 + c * 8];
            }
        }
        if (B_CHUNKS >= 256) {
            #pragma unroll
            for (int i = 0; i < B_CHUNKS / 256; ++i) {
                int idx = i * 256 + tid;
                int r = idx >> 2, c = idx & 3;
                breg[i] = *(const uint4*)&Bt[(size_t)(col0 + r) * KD + k0 + c * 8];
            }
        } else if (tid < B_CHUNKS) {
            int r = tid >> 2, c = tid & 3;
            breg[0] = *(const uint4*)&Bt[(size_t)(col0 + r) * KD + k0 + c * 8];
        }
    };
    auto writeTiles = [&]() {
        #pragma unroll
        for (int i = 0; i < A_PER; ++i) {
            int idx = i * 256 + tid;
            *(uint4*)&As[idx * 8] = areg[i];
        }
        if (B_CHUNKS >= 256) {
            #pragma unroll
            for (int i = 0; i < B_CHUNKS / 256; ++i) {
                int idx = i * 256 + tid;
                *(uint4*)&Bs[idx * 8] = breg[i];
            }
        } else if (tid < B_CHUNKS) {
            *(uint4*)&Bs[tid * 8] = breg[0];
        }
    };

    loadTiles(0);
    const int NT = KD / BK;
    for (int t = 0; t < NT; ++t) {
        __syncthreads();
        writeTiles();
        __syncthreads();
        if (t + 1 < NT) loadTiles((t + 1) * BK);
        short8 af[AM], bfr[AN];
        #pragma unroll
        for (int m = 0; m < AM; ++m)
            af[m] = *(const short8*)&As[(wm0 + m * 16 + l15) * BK + l4 * 8];
        #pragma unroll
        for (int n = 0; n < AN; ++n)
            bfr[n] = *(const short8*)&Bs[(wn0 + n * 16 + l15) * BK + l4 * 8];
        #pragma unroll
        for (int m = 0; m < AM; ++m)
            #pragma unroll
            for (int n = 0; n < AN; ++n)
                acc[m][n] = __builtin_amdgcn_mfma_f32_16x16x32_bf16(af[m], bfr[n], acc[m][n], 0, 0, 0);
    }

    float lf = 0.f;
    // C/D layout: col=lane&15, row=(lane>>4)*4+reg
    #pragma unroll
    for (int m = 0; m < AM; ++m) {
        #pragma unroll
        for (int n = 0; n < AN; ++n) {
            int gc = col0 + wn0 + n * 16 + l15;
            float bv = bias_vec ? bias_vec[gc] : 0.f;
            #pragma unroll
            for (int r = 0; r < 4; ++r) {
                int gr = row0 + wm0 + m * 16 + l4 * 4 + r;
                if (gr >= nrows) continue;
                float v = acc[m][n][r] + bv;
                if (RELU) v = fmaxf(v, 0.f);
                if (LFOCUS) lf += v * v;
                if (OUT_BF16)
                    ((unsigned short*)Cout)[(size_t)gr * ldc + gc] = f2b(v);
                else
                    ((float*)Cout)[(size_t)gr * ldc + gc] = v;
            }
        }
    }
    if (LFOCUS) {
        #pragma unroll
        for (int s = 32; s; s >>= 1) lf += __shfl_xor(lf, s);
        if ((tid & 63) == 0)
            atomicAdd(lfocus_acc, lf * (1.f / ((float)NN * KK)));
    }
}

// ---------------------------------------------------------------------------
// tilde_norm + l_sep
// ---------------------------------------------------------------------------
__global__ void tnorm_lsep_k(const float* __restrict__ tilde_phi,
                             float* __restrict__ tnorm,
                             float* __restrict__ lsep_out) {
    __shared__ float tn[KK][PHID];
    int t = threadIdx.x;
    if (t < KK * PHID) {
        float v = tilde_phi[t];
        float sq = v * v;
        #pragma unroll
        for (int s = 8; s; s >>= 1) sq += __shfl_xor(sq, s, 16);
        float tnv = v / sqrtf(sq);
        tn[t >> 4][t & 15] = tnv;
        tnorm[t] = tnv;
    }
    __syncthreads();
    if (t == 0) {
        float tot = 0.f;
        for (int i = 0; i < KK; ++i)
            for (int j = 0; j < KK; ++j) {
                float s2 = 0.f;
                for (int p = 0; p < PHID; ++p) {
                    float df = tn[i][p] - tn[j][p];
                    s2 += df * df;
                }
                tot += s2;
            }
        lsep_out[0] = tot / (float)KK;
    }
}

// ---------------------------------------------------------------------------
__global__ void degree_k(const int* __restrict__ dst, int* __restrict__ deg) {
    int e = blockIdx.x * 256 + threadIdx.x;
    if (e < EE) atomicAdd(&deg[dst[e]], 1);
}

// ---------------------------------------------------------------------------
// device-wide scan over deg[NN]
// ---------------------------------------------------------------------------
#define SCAN_NB ((NN + 255) / 256)   // 196

__global__ __launch_bounds__(256) void scan_partial_k(const int* __restrict__ deg,
                                                      int* __restrict__ bsum) {
    __shared__ int ws_[4];
    int i = blockIdx.x * 256 + threadIdx.x;
    int v = (i < NN) ? deg[i] : 0;
    int x = v;
    #pragma unroll
    for (int s = 32; s; s >>= 1) x += __shfl_xor(x, s);
    if ((threadIdx.x & 63) == 0) ws_[threadIdx.x >> 6] = x;
    __syncthreads();
    if (threadIdx.x == 0) bsum[blockIdx.x] = ws_[0] + ws_[1] + ws_[2] + ws_[3];
}

__global__ __launch_bounds__(256) void scan_bsum_k(int* __restrict__ bsum) {
    __shared__ int sd[256];
    int t = threadIdx.x;
    int v = (t < SCAN_NB) ? bsum[t] : 0;
    sd[t] = v;
    __syncthreads();
    for (int s = 1; s < 256; s <<= 1) {
        int u = (t >= s) ? sd[t - s] : 0;
        __syncthreads();
        sd[t] += u;
        __syncthreads();
    }
    if (t < SCAN_NB) bsum[t] = sd[t] - v;   // exclusive
}

__global__ __launch_bounds__(256) void scan_scatter_k(const int* __restrict__ deg,
                                                      const int* __restrict__ bsum,
                                                      int* __restrict__ offs,
                                                      int* __restrict__ cursor) {
    __shared__ int wexc[4];
    int i = blockIdx.x * 256 + threadIdx.x;
    int lane = threadIdx.x & 63, wid = threadIdx.x >> 6;
    int v = (i < NN) ? deg[i] : 0;
    int x = v;
    #pragma unroll
    for (int d = 1; d < 64; d <<= 1) { int u = __shfl_up(x, d); if (lane >= d) x += u; }
    if (lane == 63) wexc[wid] = x;
    __syncthreads();
    if (threadIdx.x == 0) {
        int a = wexc[0], b = wexc[1], c = wexc[2];
        wexc[0] = 0; wexc[1] = a; wexc[2] = a + b; wexc[3] = a + b + c;
    }
    __syncthreads();
    int excl = (x - v) + wexc[wid] + bsum[blockIdx.x];
    if (i < NN) {
        cursor[i] = excl;
        offs[i + 1] = excl + v;
        if (i == 0) offs[0] = 0;
    }
}

// ---------------------------------------------------------------------------
// CSR scatter: src + dst per slot
// ---------------------------------------------------------------------------
__global__ void scatter_src_k(const int* __restrict__ src, const int* __restrict__ dst,
                              int* __restrict__ cursor, int* __restrict__ csr_src,
                              int* __restrict__ csr_dst) {
    int e = blockIdx.x * 256 + threadIdx.x;
    if (e >= EE) return;
    int d = dst[e];
    int pos = atomicAdd(&cursor[d], 1);
    csr_src[pos] = src[e];
    csr_dst[pos] = d;
}

// ---------------------------------------------------------------------------
// edge weights, thread per CSR slot. Consecutive slots share dst ->
// delta[d]/phi[d] are L1-broadcast-hot. Coalesced float4 write, no atomics.
// ---------------------------------------------------------------------------
__global__ __launch_bounds__(256) void edge_w_k(const int* __restrict__ csr_src,
                                                const int* __restrict__ csr_dst,
                                                const float* __restrict__ phi,
                                                const float* __restrict__ delta,
                                                const float* __restrict__ tnorm,
                                                float4* __restrict__ csr_w) {
    __shared__ float tn[KK * PHID];
    if (threadIdx.x < KK * PHID) tn[threadIdx.x] = tnorm[threadIdx.x];
    __syncthreads();
    int e = blockIdx.x * 256 + threadIdx.x;
    if (e >= EE) return;
    int s = csr_src[e], d = csr_dst[e];
    const float4* ps4 = (const float4*)(phi + (size_t)s * 16);
    const float4* pd4 = (const float4*)(phi + (size_t)d * 16);
    float dv[16];
    float nrm2 = 0.f;
    #pragma unroll
    for (int q = 0; q < 4; ++q) {
        float4 a = ps4[q], b = pd4[q];
        dv[q * 4 + 0] = a.x - b.x;
        dv[q * 4 + 1] = a.y - b.y;
        dv[q * 4 + 2] = a.z - b.z;
        dv[q * 4 + 3] = a.w - b.w;
    }
    #pragma unroll
    for (int p = 0; p < 15; ++p) nrm2 += dv[p] * dv[p];
    float z = (nrm2 == 0.f) ? 1.f : 0.f;       // coincident-edge mask
    dv[15] = z;
    nrm2 += z;
    float inv = 1.f / fmaxf(sqrtf(nrm2), 1e-8f);
    const float* dl = delta + (size_t)d * 64;
    float res[4];
    #pragma unroll
    for (int k = 0; k < 4; ++k) {
        const float4* dk = (const float4*)(dl + k * 16);
        float sacc = 0.f;
        #pragma unroll
        for (int q = 0; q < 4; ++q) {
            float4 tv = dk[q];
            sacc += dv[q * 4 + 0] * (tn[k * 16 + q * 4 + 0] + tv.x);
            sacc += dv[q * 4 + 1] * (tn[k * 16 + q * 4 + 1] + tv.y);
            sacc += dv[q * 4 + 2] * (tn[k * 16 + q * 4 + 2] + tv.z);
            sacc += dv[q * 4 + 3] * (tn[k * 16 + q * 4 + 3] + tv.w);
        }
        res[k] = sacc * inv;
    }
    csr_w[e] = make_float4(__expf(res[0]), __expf(res[1]),
                           __expf(res[2]), __expf(res[3]));
}

// ---------------------------------------------------------------------------
// per-dst single-pass aggregation. Wave per node, lane = channel.
// h layout is [node][ch][k] -> one ushort4 gather per lane per edge.
// ---------------------------------------------------------------------------
__global__ __launch_bounds__(256) void aggregate_k(const int* __restrict__ offs,
                                                   const int* __restrict__ csr_src,
                                                   const float4* __restrict__ csr_w,
                                                   const unsigned short* __restrict__ h,
                                                   const float* __restrict__ bias,
                                                   float* __restrict__ out) {
    int wave = threadIdx.x >> 6;
    int lane = threadIdx.x & 63;
    int n = blockIdx.x * 4 + wave;
    if (n >= NN) return;
    int beg = offs[n], end = offs[n + 1];

    float a0 = 0.f, a1 = 0.f, a2 = 0.f, a3 = 0.f;
    float d0 = 0.f, d1 = 0.f, d2 = 0.f, d3 = 0.f;
    int p = beg;
    for (; p + 1 < end; p += 2) {
        float4 wA = csr_w[p];
        float4 wB = csr_w[p + 1];
        int sA = csr_src[p];
        int sB = csr_src[p + 1];
        ushort4 hA = *(const ushort4*)&h[(size_t)sA * 256 + (lane << 2)];
        ushort4 hB = *(const ushort4*)&h[(size_t)sB * 256 + (lane << 2)];
        d0 += wA.x + wB.x; d1 += wA.y + wB.y;
        d2 += wA.z + wB.z; d3 += wA.w + wB.w;
        a0 += wA.x * b2f(hA.x) + wB.x * b2f(hB.x);
        a1 += wA.y * b2f(hA.y) + wB.y * b2f(hB.y);
        a2 += wA.z * b2f(hA.z) + wB.z * b2f(hB.z);
        a3 += wA.w * b2f(hA.w) + wB.w * b2f(hB.w);
    }
    if (p < end) {
        float4 wA = csr_w[p];
        int sA = csr_src[p];
        ushort4 hA = *(const ushort4*)&h[(size_t)sA * 256 + (lane << 2)];
        d0 += wA.x; d1 += wA.y; d2 += wA.z; d3 += wA.w;
        a0 += wA.x * b2f(hA.x);
        a1 += wA.y * b2f(hA.y);
        a2 += wA.z * b2f(hA.z);
        a3 += wA.w * b2f(hA.w);
    }
    float v = (d0 > 0.f ? a0 / d0 : 0.f) + (d1 > 0.f ? a1 / d1 : 0.f) +
              (d2 > 0.f ? a2 / d2 : 0.f) + (d3 > 0.f ? a3 / d3 : 0.f) + bias[lane];
    float nr = v * v;
    #pragma unroll
    for (int s = 32; s; s >>= 1) nr += __shfl_xor(nr, s);
    float invn = 1.f / fmaxf(sqrtf(nr), 1e-8f);
    out[(size_t)n * 64 + lane] = v * invn;
}

// ---------------------------------------------------------------------------
extern "C" void kernel_launch(void* const* d_in, const int* in_sizes, int n_in,
                              void* d_out, int out_size, void* d_ws, size_t ws_size,
                              hipStream_t stream) {
    const float* h_l       = (const float*)d_in[0];
    const float* e_l       = (const float*)d_in[1];
    const int*   src       = (const int*)d_in[2];
    const int*   dst       = (const int*)d_in[3];
    const float* W_phi     = (const float*)d_in[4];
    const float* W1        = (const float*)d_in[5];
    const float* b1        = (const float*)d_in[6];
    const float* W2        = (const float*)d_in[7];
    const float* b2        = (const float*)d_in[8];
    const float* tilde_phi = (const float*)d_in[9];
    const float* W         = (const float*)d_in[10];
    const float* bias      = (const float*)d_in[11];
    float* out = (float*)d_out;
    float* lsep_ptr   = out + (size_t)NN * OUTD;
    float* lfocus_ptr = out + (size_t)NN * OUTD + 1;

    char* ws = (char*)d_ws;
    size_t off = 0;
    auto alloc = [&](size_t bytes) -> char* {
        char* p = ws + off;
        off += (bytes + 255) & ~(size_t)255;
        return p;
    };
    float*          phi     = (float*)alloc((size_t)NN * 16 * 4);
    float*          delta   = (float*)alloc((size_t)NN * 64 * 4);
    unsigned short* h_bf    = (unsigned short*)alloc((size_t)NN * 256 * 2);
    unsigned short* hid_bf  = (unsigned short*)alloc((size_t)NN * 256 * 2);
    int*            csr_src = (int*)alloc((size_t)EE * 4);
    int*            csr_dst = (int*)alloc((size_t)EE * 4);
    float*          csr_w   = (float*)alloc((size_t)EE * 4 * 4);
    int*            deg     = (int*)alloc((size_t)NN * 4);
    int*            offs    = (int*)alloc((size_t)(NN + 1) * 4);
    int*            cursor  = (int*)alloc((size_t)NN * 4);
    int*            bsum    = (int*)alloc((size_t)SCAN_NB * 4);
    unsigned short* W_t     = (unsigned short*)alloc(256 * 256 * 2);
    unsigned short* W1_bf   = (unsigned short*)alloc(256 * 128 * 2);
    unsigned short* W2_bf   = (unsigned short*)alloc(64 * 256 * 2);
    unsigned short* Wphi_t  = (unsigned short*)alloc(16 * 128 * 2);
    float*          tnorm   = (float*)alloc(64 * 4);

    hipMemsetAsync(deg, 0, (size_t)NN * 4, stream);

    tnorm_lsep_k<<<1, 64, 0, stream>>>(tilde_phi, tnorm, lsep_ptr);
    wprep_k<<<(116736 + 255) / 256, 256, 0, stream>>>(W, W1, W2, W_phi, W_t, W1_bf,
                                                      W2_bf, Wphi_t, lfocus_ptr);

    const int MB = (NN + 127) / 128;   // 391
    // phi = e_l @ W_phi (padded to 16 cols)
    mgemm_k<128, 16, 1, 2, 1, false, false, true, false>
        <<<dim3(MB, 1), 256, 0, stream>>>(e_l, Wphi_t, nullptr, phi, NN, 16, nullptr);
    // hid = relu(e_l @ W1^T + b1) -> bf16
    mgemm_k<128, 128, 2, 4, 4, true, true, true, false>
        <<<dim3(MB, 2), 256, 0, stream>>>(e_l, W1_bf, b1, hid_bf, NN, 256, nullptr);
    // delta = hid @ W2^T + b2 -> f32, fused l_focus
    mgemm_k<256, 64, 1, 2, 4, false, false, false, true>
        <<<dim3(MB, 1), 256, 0, stream>>>(hid_bf, W2_bf, b2, delta, NN, 64, lfocus_ptr);
    // h = h_l @ W -> bf16, [ch][k]-interleaved layout
    mgemm_k<256, 128, 2, 4, 4, false, true, true, false>
        <<<dim3(MB, 2), 256, 0, stream>>>(h_l, W_t, nullptr, h_bf, NN, 256, nullptr);

    // CSR build
    degree_k<<<3125, 256, 0, stream>>>(dst, deg);
    scan_partial_k<<<SCAN_NB, 256, 0, stream>>>(deg, bsum);
    scan_bsum_k<<<1, 256, 0, stream>>>(bsum);
    scan_scatter_k<<<SCAN_NB, 256, 0, stream>>>(deg, bsum, offs, cursor);
    scatter_src_k<<<3125, 256, 0, stream>>>(src, dst, cursor, csr_src, csr_dst);

    // edge weights (thread-per-slot, CSR-ordered)
    edge_w_k<<<3125, 256, 0, stream>>>(csr_src, csr_dst, phi, delta, tnorm,
                                       (float4*)csr_w);

    // per-dst single-pass softmax + aggregation + normalize
    aggregate_k<<<12500, 256, 0, stream>>>(offs, csr_src, (const float4*)csr_w, h_bf,
                                           bias, out);
}

// Round 8
// 312.172 us; speedup vs baseline: 1.6650x; 1.0428x over previous
//
#include <hip/hip_runtime.h>
#include <math.h>

#define NN 50000
#define EE 800000
#define RAWD 128
#define HIDD 256
#define OUTD 64
#define KK 4
#define PHID 16

typedef __attribute__((ext_vector_type(8))) short short8;
typedef __attribute__((ext_vector_type(4))) float f32x4;

__device__ inline float b2f(unsigned short u) {
    union { unsigned i; float f; } v; v.i = ((unsigned)u) << 16; return v.f;
}
__device__ inline unsigned short f2b(float f) {
    unsigned u = __float_as_uint(f);
    unsigned r = (u + 0x7FFFu + ((u >> 16) & 1u)) >> 16;   // RNE
    return (unsigned short)r;
}
__device__ inline unsigned char f2fp8(float v) {
    return (unsigned char)(__builtin_amdgcn_cvt_pk_fp8_f32(v, v, 0, false) & 0xFF);
}

// ---------------------------------------------------------------------------
// weight prep: W_t (perm: row cp=ch*4+k), W1, W2, Wphi_t (+pad), zero l_focus
// ---------------------------------------------------------------------------
__global__ void wprep_k(const float* __restrict__ W, const float* __restrict__ W1,
                        const float* __restrict__ W2, const float* __restrict__ W_phi,
                        unsigned short* __restrict__ W_t, unsigned short* __restrict__ W1_bf,
                        unsigned short* __restrict__ W2_bf, unsigned short* __restrict__ Wphi_t,
                        float* __restrict__ lfocus_zero) {
    int i = blockIdx.x * 256 + threadIdx.x;
    if (i == 0) *lfocus_zero = 0.f;
    if (i < 65536) {
        int cp = i >> 8, r = i & 255;
        int ch = cp >> 2, k = cp & 3;
        W_t[i] = f2b(W[(size_t)r * 256 + (k << 6) + ch]);
    } else if (i < 65536 + 32768) {
        int j = i - 65536;
        W1_bf[j] = f2b(W1[j]);
    } else if (i < 65536 + 32768 + 16384) {
        int j = i - 98304;
        W2_bf[j] = f2b(W2[j]);
    } else if (i < 65536 + 32768 + 16384 + 2048) {
        int j = i - 114688;
        int cp = j >> 7, r = j & 127;
        Wphi_t[j] = (cp < 15) ? f2b(W_phi[(size_t)r * 15 + cp]) : (unsigned short)0;
    }
}

// ---------------------------------------------------------------------------
// tilde_norm + l_sep
// ---------------------------------------------------------------------------
__global__ void tnorm_lsep_k(const float* __restrict__ tilde_phi,
                             float* __restrict__ tnorm,
                             float* __restrict__ lsep_out) {
    __shared__ float tn[KK][PHID];
    int t = threadIdx.x;
    if (t < KK * PHID) {
        float v = tilde_phi[t];
        float sq = v * v;
        #pragma unroll
        for (int s = 8; s; s >>= 1) sq += __shfl_xor(sq, s, 16);
        float tnv = v / sqrtf(sq);
        tn[t >> 4][t & 15] = tnv;
        tnorm[t] = tnv;
    }
    __syncthreads();
    if (t == 0) {
        float tot = 0.f;
        for (int i = 0; i < KK; ++i)
            for (int j = 0; j < KK; ++j) {
                float s2 = 0.f;
                for (int p = 0; p < PHID; ++p) {
                    float df = tn[i][p] - tn[j][p];
                    s2 += df * df;
                }
                tot += s2;
            }
        lsep_out[0] = tot / (float)KK;
    }
}

// ---------------------------------------------------------------------------
// hgemm: BM=64, BN=256 (single col pass, A f32 read ONCE), 256 thr / 4 waves.
// Wave w covers cols [w*64, w*64+64). AM=4, AN=4. Out bf16 or fp8.
// ---------------------------------------------------------------------------
template <int KD, bool RELU, bool OUT_FP8>
__global__ __launch_bounds__(256) void hgemm_k(const float* __restrict__ A,
                                               const unsigned short* __restrict__ Bt,
                                               const float* __restrict__ bias_vec,
                                               void* __restrict__ Cout) {
    const int BM = 64, BK = 32;
    __shared__ __align__(16) unsigned short As[BM * BK];
    __shared__ __align__(16) unsigned short Bs[256 * BK];
    const int tid = threadIdx.x;
    const int w = tid >> 6, l = tid & 63;
    const int row0 = blockIdx.x * BM;
    const int wn0 = w * 64;
    const int l15 = l & 15, l4 = l >> 4;

    const int ar = tid >> 2, ak = (tid & 3) * 8;
    int arow = row0 + ar; if (arow >= NN) arow = NN - 1;

    float4 fa0, fa1;
    uint4 breg[4];
    f32x4 acc[4][4];
    #pragma unroll
    for (int m = 0; m < 4; ++m)
        #pragma unroll
        for (int n = 0; n < 4; ++n)
            acc[m][n] = (f32x4){0.f, 0.f, 0.f, 0.f};

    auto loadT = [&](int k0) {
        const float* Af = A + (size_t)arow * KD + k0 + ak;
        fa0 = *(const float4*)Af;
        fa1 = *(const float4*)(Af + 4);
        #pragma unroll
        for (int i = 0; i < 4; ++i) {
            int c = tid + i * 256;
            breg[i] = *(const uint4*)&Bt[(size_t)(c >> 2) * KD + k0 + (c & 3) * 8];
        }
    };
    auto writeT = [&]() {
        unsigned u0 = f2b(fa0.x) | ((unsigned)f2b(fa0.y) << 16);
        unsigned u1 = f2b(fa0.z) | ((unsigned)f2b(fa0.w) << 16);
        unsigned u2 = f2b(fa1.x) | ((unsigned)f2b(fa1.y) << 16);
        unsigned u3 = f2b(fa1.z) | ((unsigned)f2b(fa1.w) << 16);
        *(uint4*)&As[ar * 32 + ak] = make_uint4(u0, u1, u2, u3);
        #pragma unroll
        for (int i = 0; i < 4; ++i) {
            int c = tid + i * 256;
            *(uint4*)&Bs[(c >> 2) * 32 + (c & 3) * 8] = breg[i];
        }
    };

    loadT(0);
    const int NT = KD / BK;
    for (int t = 0; t < NT; ++t) {
        __syncthreads();
        writeT();
        __syncthreads();
        if (t + 1 < NT) loadT((t + 1) * BK);
        short8 af[4], bfr[4];
        #pragma unroll
        for (int m = 0; m < 4; ++m)
            af[m] = *(const short8*)&As[(m * 16 + l15) * 32 + l4 * 8];
        #pragma unroll
        for (int n = 0; n < 4; ++n)
            bfr[n] = *(const short8*)&Bs[(wn0 + n * 16 + l15) * 32 + l4 * 8];
        #pragma unroll
        for (int m = 0; m < 4; ++m)
            #pragma unroll
            for (int n = 0; n < 4; ++n)
                acc[m][n] = __builtin_amdgcn_mfma_f32_16x16x32_bf16(af[m], bfr[n], acc[m][n], 0, 0, 0);
    }

    #pragma unroll
    for (int m = 0; m < 4; ++m) {
        #pragma unroll
        for (int n = 0; n < 4; ++n) {
            int gc = wn0 + n * 16 + l15;
            float bv = bias_vec ? bias_vec[gc] : 0.f;
            #pragma unroll
            for (int r = 0; r < 4; ++r) {
                int gr = row0 + m * 16 + l4 * 4 + r;
                if (gr >= NN) continue;
                float v = acc[m][n][r] + bv;
                if (RELU) v = fmaxf(v, 0.f);
                if (OUT_FP8)
                    ((unsigned char*)Cout)[(size_t)gr * 256 + gc] = f2fp8(v);
                else
                    ((unsigned short*)Cout)[(size_t)gr * 256 + gc] = f2b(v);
            }
        }
    }
}

// ---------------------------------------------------------------------------
// mgemm (BM=128): used for phi (BN=16) and delta (BN=64, TNADJ+LFOCUS).
// ---------------------------------------------------------------------------
template <int KD, int BN, int WN_WAVES, int AM, int AN, bool RELU, bool OUT_BF16,
          bool AF32, bool LFOCUS, bool TNADJ>
__global__ __launch_bounds__(256) void mgemm_k(const void* __restrict__ A,
                                               const unsigned short* __restrict__ Bt,
                                               const float* __restrict__ bias_vec,
                                               void* __restrict__ Cout,
                                               int nrows, int ldc,
                                               float* __restrict__ lfocus_acc,
                                               const float* __restrict__ tn_vec) {
    const int BM = 128, BK = 32;
    __shared__ __align__(16) unsigned short As[BM * BK];
    __shared__ __align__(16) unsigned short Bs[BN * BK];
    const int tid = threadIdx.x;
    const int w = tid >> 6, l = tid & 63;
    const int row0 = blockIdx.x * BM;
    const int col0 = blockIdx.y * BN;
    const int wr = w / WN_WAVES, wc = w % WN_WAVES;
    const int wm0 = wr * (AM * 16), wn0 = wc * (AN * 16);
    const int l15 = l & 15, l4 = l >> 4;

    const int A_PER = (BM * 4) / 256;          // 2
    const int B_CHUNKS = BN * 4;

    uint4 areg[A_PER];
    uint4 breg[(B_CHUNKS + 255) / 256];

    f32x4 acc[AM][AN];
    #pragma unroll
    for (int m = 0; m < AM; ++m)
        #pragma unroll
        for (int n = 0; n < AN; ++n)
            acc[m][n] = (f32x4){0.f, 0.f, 0.f, 0.f};

    auto loadTiles = [&](int k0) {
        #pragma unroll
        for (int i = 0; i < A_PER; ++i) {
            int idx = i * 256 + tid;
            int r = idx >> 2, c = idx & 3;
            int gr = row0 + r; if (gr >= nrows) gr = nrows - 1;
            if (AF32) {
                const float* Af = (const float*)A + (size_t)gr * KD + k0 + c * 8;
                float4 f0 = *(const float4*)Af;
                float4 f1 = *(const float4*)(Af + 4);
                unsigned u0 = f2b(f0.x) | ((unsigned)f2b(f0.y) << 16);
                unsigned u1 = f2b(f0.z) | ((unsigned)f2b(f0.w) << 16);
                unsigned u2 = f2b(f1.x) | ((unsigned)f2b(f1.y) << 16);
                unsigned u3 = f2b(f1.z) | ((unsigned)f2b(f1.w) << 16);
                areg[i] = make_uint4(u0, u1, u2, u3);
            } else {
                areg[i] = *(const uint4*)&((const unsigned short*)A)[(size_t)gr * KD + k0 + c * 8];
            }
        }
        if (B_CHUNKS >= 256) {
            #pragma unroll
            for (int i = 0; i < B_CHUNKS / 256; ++i) {
                int idx = i * 256 + tid;
                int r = idx >> 2, c = idx & 3;
                breg[i] = *(const uint4*)&Bt[(size_t)(col0 + r) * KD + k0 + c * 8];
            }
        } else if (tid < B_CHUNKS) {
            int r = tid >> 2, c = tid & 3;
            breg[0] = *(const uint4*)&Bt[(size_t)(col0 + r) * KD + k0 + c * 8];
        }
    };
    auto writeTiles = [&]() {
        #pragma unroll
        for (int i = 0; i < A_PER; ++i) {
            int idx = i * 256 + tid;
            *(uint4*)&As[idx * 8] = areg[i];
        }
        if (B_CHUNKS >= 256) {
            #pragma unroll
            for (int i = 0; i < B_CHUNKS / 256; ++i) {
                int idx = i * 256 + tid;
                *(uint4*)&Bs[idx * 8] = breg[i];
            }
        } else if (tid < B_CHUNKS) {
            *(uint4*)&Bs[tid * 8] = breg[0];
        }
    };

    loadTiles(0);
    const int NT = KD / BK;
    for (int t = 0; t < NT; ++t) {
        __syncthreads();
        writeTiles();
        __syncthreads();
        if (t + 1 < NT) loadTiles((t + 1) * BK);
        short8 af[AM], bfr[AN];
        #pragma unroll
        for (int m = 0; m < AM; ++m)
            af[m] = *(const short8*)&As[(wm0 + m * 16 + l15) * BK + l4 * 8];
        #pragma unroll
        for (int n = 0; n < AN; ++n)
            bfr[n] = *(const short8*)&Bs[(wn0 + n * 16 + l15) * BK + l4 * 8];
        #pragma unroll
        for (int m = 0; m < AM; ++m)
            #pragma unroll
            for (int n = 0; n < AN; ++n)
                acc[m][n] = __builtin_amdgcn_mfma_f32_16x16x32_bf16(af[m], bfr[n], acc[m][n], 0, 0, 0);
    }

    float lf = 0.f;
    #pragma unroll
    for (int m = 0; m < AM; ++m) {
        #pragma unroll
        for (int n = 0; n < AN; ++n) {
            int gc = col0 + wn0 + n * 16 + l15;
            float bv = bias_vec ? bias_vec[gc] : 0.f;
            float tv = TNADJ ? tn_vec[gc] : 0.f;
            #pragma unroll
            for (int r = 0; r < 4; ++r) {
                int gr = row0 + wm0 + m * 16 + l4 * 4 + r;
                if (gr >= nrows) continue;
                float v = acc[m][n][r] + bv;
                if (RELU) v = fmaxf(v, 0.f);
                if (LFOCUS) lf += v * v;
                if (TNADJ) v += tv;
                if (OUT_BF16)
                    ((unsigned short*)Cout)[(size_t)gr * ldc + gc] = f2b(v);
                else
                    ((float*)Cout)[(size_t)gr * ldc + gc] = v;
            }
        }
    }
    if (LFOCUS) {
        #pragma unroll
        for (int s = 32; s; s >>= 1) lf += __shfl_xor(lf, s);
        if ((tid & 63) == 0)
            atomicAdd(lfocus_acc, lf * (1.f / ((float)NN * KK)));
    }
}

// ---------------------------------------------------------------------------
__global__ void degree_k(const int* __restrict__ dst, int* __restrict__ deg) {
    int e = blockIdx.x * 256 + threadIdx.x;
    if (e < EE) atomicAdd(&deg[dst[e]], 1);
}

#define SCAN_NB ((NN + 255) / 256)   // 196

__global__ __launch_bounds__(256) void scan_partial_k(const int* __restrict__ deg,
                                                      int* __restrict__ bsum) {
    __shared__ int ws_[4];
    int i = blockIdx.x * 256 + threadIdx.x;
    int v = (i < NN) ? deg[i] : 0;
    int x = v;
    #pragma unroll
    for (int s = 32; s; s >>= 1) x += __shfl_xor(x, s);
    if ((threadIdx.x & 63) == 0) ws_[threadIdx.x >> 6] = x;
    __syncthreads();
    if (threadIdx.x == 0) bsum[blockIdx.x] = ws_[0] + ws_[1] + ws_[2] + ws_[3];
}

__global__ __launch_bounds__(256) void scan_bsum_k(int* __restrict__ bsum) {
    __shared__ int sd[256];
    int t = threadIdx.x;
    int v = (t < SCAN_NB) ? bsum[t] : 0;
    sd[t] = v;
    __syncthreads();
    for (int s = 1; s < 256; s <<= 1) {
        int u = (t >= s) ? sd[t - s] : 0;
        __syncthreads();
        sd[t] += u;
        __syncthreads();
    }
    if (t < SCAN_NB) bsum[t] = sd[t] - v;   // exclusive
}

__global__ __launch_bounds__(256) void scan_scatter_k(const int* __restrict__ deg,
                                                      const int* __restrict__ bsum,
                                                      int* __restrict__ offs,
                                                      int* __restrict__ cursor) {
    __shared__ int wexc[4];
    int i = blockIdx.x * 256 + threadIdx.x;
    int lane = threadIdx.x & 63, wid = threadIdx.x >> 6;
    int v = (i < NN) ? deg[i] : 0;
    int x = v;
    #pragma unroll
    for (int d = 1; d < 64; d <<= 1) { int u = __shfl_up(x, d); if (lane >= d) x += u; }
    if (lane == 63) wexc[wid] = x;
    __syncthreads();
    if (threadIdx.x == 0) {
        int a = wexc[0], b = wexc[1], c = wexc[2];
        wexc[0] = 0; wexc[1] = a; wexc[2] = a + b; wexc[3] = a + b + c;
    }
    __syncthreads();
    int excl = (x - v) + wexc[wid] + bsum[blockIdx.x];
    if (i < NN) {
        cursor[i] = excl;
        offs[i + 1] = excl + v;
        if (i == 0) offs[0] = 0;
    }
}

__global__ void scatter_src_k(const int* __restrict__ src, const int* __restrict__ dst,
                              int* __restrict__ cursor, int* __restrict__ csr_src,
                              int* __restrict__ csr_dst) {
    int e = blockIdx.x * 256 + threadIdx.x;
    if (e >= EE) return;
    int d = dst[e];
    int pos = atomicAdd(&cursor[d], 1);
    csr_src[pos] = src[e];
    csr_dst[pos] = d;
}

// ---------------------------------------------------------------------------
// edge weights, thread per CSR slot. delta' already includes tnorm.
// ---------------------------------------------------------------------------
__global__ __launch_bounds__(256) void edge_w_k(const int* __restrict__ csr_src,
                                                const int* __restrict__ csr_dst,
                                                const float* __restrict__ phi,
                                                const float* __restrict__ deltap,
                                                float4* __restrict__ csr_w) {
    int e = blockIdx.x * 256 + threadIdx.x;
    if (e >= EE) return;
    int s = csr_src[e], d = csr_dst[e];
    const float4* ps4 = (const float4*)(phi + (size_t)s * 16);
    const float4* pd4 = (const float4*)(phi + (size_t)d * 16);
    float dv[16];
    float nrm2 = 0.f;
    #pragma unroll
    for (int q = 0; q < 4; ++q) {
        float4 a = ps4[q], b = pd4[q];
        dv[q * 4 + 0] = a.x - b.x;
        dv[q * 4 + 1] = a.y - b.y;
        dv[q * 4 + 2] = a.z - b.z;
        dv[q * 4 + 3] = a.w - b.w;
    }
    #pragma unroll
    for (int p = 0; p < 15; ++p) nrm2 += dv[p] * dv[p];
    float z = (nrm2 == 0.f) ? 1.f : 0.f;
    dv[15] = z;
    nrm2 += z;
    float inv = 1.f / fmaxf(sqrtf(nrm2), 1e-8f);
    const float* dl = deltap + (size_t)d * 64;
    float res[4];
    #pragma unroll
    for (int k = 0; k < 4; ++k) {
        const float4* dk = (const float4*)(dl + k * 16);
        float sacc = 0.f;
        #pragma unroll
        for (int q = 0; q < 4; ++q) {
            float4 tv = dk[q];
            sacc += dv[q * 4 + 0] * tv.x;
            sacc += dv[q * 4 + 1] * tv.y;
            sacc += dv[q * 4 + 2] * tv.z;
            sacc += dv[q * 4 + 3] * tv.w;
        }
        res[k] = sacc * inv;
    }
    csr_w[e] = make_float4(__expf(res[0]), __expf(res[1]),
                           __expf(res[2]), __expf(res[3]));
}

// ---------------------------------------------------------------------------
// per-dst single-pass aggregation. Wave per node, lane = channel.
// h is fp8 [node][ch][k]: one uint (4 fp8) gather per lane per edge.
// ---------------------------------------------------------------------------
__global__ __launch_bounds__(256) void aggregate_k(const int* __restrict__ offs,
                                                   const int* __restrict__ csr_src,
                                                   const float4* __restrict__ csr_w,
                                                   const unsigned int* __restrict__ h8,
                                                   const float* __restrict__ bias,
                                                   float* __restrict__ out) {
    int wave = threadIdx.x >> 6;
    int lane = threadIdx.x & 63;
    int n = blockIdx.x * 4 + wave;
    if (n >= NN) return;
    int beg = offs[n], end = offs[n + 1];

    float a0 = 0.f, a1 = 0.f, a2 = 0.f, a3 = 0.f;
    float d0 = 0.f, d1 = 0.f, d2 = 0.f, d3 = 0.f;
    int p = beg;
    for (; p + 3 < end; p += 4) {
        float4 w0 = csr_w[p], w1 = csr_w[p + 1], w2 = csr_w[p + 2], w3 = csr_w[p + 3];
        int s0 = csr_src[p], s1 = csr_src[p + 1], s2 = csr_src[p + 2], s3 = csr_src[p + 3];
        unsigned hv0 = h8[(size_t)s0 * 64 + lane];
        unsigned hv1 = h8[(size_t)s1 * 64 + lane];
        unsigned hv2 = h8[(size_t)s2 * 64 + lane];
        unsigned hv3 = h8[(size_t)s3 * 64 + lane];
        d0 += (w0.x + w1.x) + (w2.x + w3.x);
        d1 += (w0.y + w1.y) + (w2.y + w3.y);
        d2 += (w0.z + w1.z) + (w2.z + w3.z);
        d3 += (w0.w + w1.w) + (w2.w + w3.w);
        a0 += w0.x * __builtin_amdgcn_cvt_f32_fp8(hv0, 0) + w1.x * __builtin_amdgcn_cvt_f32_fp8(hv1, 0)
            + w2.x * __builtin_amdgcn_cvt_f32_fp8(hv2, 0) + w3.x * __builtin_amdgcn_cvt_f32_fp8(hv3, 0);
        a1 += w0.y * __builtin_amdgcn_cvt_f32_fp8(hv0, 1) + w1.y * __builtin_amdgcn_cvt_f32_fp8(hv1, 1)
            + w2.y * __builtin_amdgcn_cvt_f32_fp8(hv2, 1) + w3.y * __builtin_amdgcn_cvt_f32_fp8(hv3, 1);
        a2 += w0.z * __builtin_amdgcn_cvt_f32_fp8(hv0, 2) + w1.z * __builtin_amdgcn_cvt_f32_fp8(hv1, 2)
            + w2.z * __builtin_amdgcn_cvt_f32_fp8(hv2, 2) + w3.z * __builtin_amdgcn_cvt_f32_fp8(hv3, 2);
        a3 += w0.w * __builtin_amdgcn_cvt_f32_fp8(hv0, 3) + w1.w * __builtin_amdgcn_cvt_f32_fp8(hv1, 3)
            + w2.w * __builtin_amdgcn_cvt_f32_fp8(hv2, 3) + w3.w * __builtin_amdgcn_cvt_f32_fp8(hv3, 3);
    }
    for (; p < end; ++p) {
        float4 wA = csr_w[p];
        int sA = csr_src[p];
        unsigned hv = h8[(size_t)sA * 64 + lane];
        d0 += wA.x; d1 += wA.y; d2 += wA.z; d3 += wA.w;
        a0 += wA.x * __builtin_amdgcn_cvt_f32_fp8(hv, 0);
        a1 += wA.y * __builtin_amdgcn_cvt_f32_fp8(hv, 1);
        a2 += wA.z * __builtin_amdgcn_cvt_f32_fp8(hv, 2);
        a3 += wA.w * __builtin_amdgcn_cvt_f32_fp8(hv, 3);
    }
    float v = (d0 > 0.f ? a0 / d0 : 0.f) + (d1 > 0.f ? a1 / d1 : 0.f) +
              (d2 > 0.f ? a2 / d2 : 0.f) + (d3 > 0.f ? a3 / d3 : 0.f) + bias[lane];
    float nr = v * v;
    #pragma unroll
    for (int s = 32; s; s >>= 1) nr += __shfl_xor(nr, s);
    float invn = 1.f / fmaxf(sqrtf(nr), 1e-8f);
    out[(size_t)n * 64 + lane] = v * invn;
}

// ---------------------------------------------------------------------------
extern "C" void kernel_launch(void* const* d_in, const int* in_sizes, int n_in,
                              void* d_out, int out_size, void* d_ws, size_t ws_size,
                              hipStream_t stream) {
    const float* h_l       = (const float*)d_in[0];
    const float* e_l       = (const float*)d_in[1];
    const int*   src       = (const int*)d_in[2];
    const int*   dst       = (const int*)d_in[3];
    const float* W_phi     = (const float*)d_in[4];
    const float* W1        = (const float*)d_in[5];
    const float* b1        = (const float*)d_in[6];
    const float* W2        = (const float*)d_in[7];
    const float* b2        = (const float*)d_in[8];
    const float* tilde_phi = (const float*)d_in[9];
    const float* W         = (const float*)d_in[10];
    const float* bias      = (const float*)d_in[11];
    float* out = (float*)d_out;
    float* lsep_ptr   = out + (size_t)NN * OUTD;
    float* lfocus_ptr = out + (size_t)NN * OUTD + 1;

    char* ws = (char*)d_ws;
    size_t off = 0;
    auto alloc = [&](size_t bytes) -> char* {
        char* p = ws + off;
        off += (bytes + 255) & ~(size_t)255;
        return p;
    };
    float*          phi     = (float*)alloc((size_t)NN * 16 * 4);
    float*          deltap  = (float*)alloc((size_t)NN * 64 * 4);
    unsigned char*  h8      = (unsigned char*)alloc((size_t)NN * 256);
    unsigned short* hid_bf  = (unsigned short*)alloc((size_t)NN * 256 * 2);
    int*            csr_src = (int*)alloc((size_t)EE * 4);
    int*            csr_dst = (int*)alloc((size_t)EE * 4);
    float*          csr_w   = (float*)alloc((size_t)EE * 4 * 4);
    int*            deg     = (int*)alloc((size_t)NN * 4);
    int*            offs    = (int*)alloc((size_t)(NN + 1) * 4);
    int*            cursor  = (int*)alloc((size_t)NN * 4);
    int*            bsum    = (int*)alloc((size_t)SCAN_NB * 4);
    unsigned short* W_t     = (unsigned short*)alloc(256 * 256 * 2);
    unsigned short* W1_bf   = (unsigned short*)alloc(256 * 128 * 2);
    unsigned short* W2_bf   = (unsigned short*)alloc(64 * 256 * 2);
    unsigned short* Wphi_t  = (unsigned short*)alloc(16 * 128 * 2);
    float*          tnorm   = (float*)alloc(64 * 4);

    hipMemsetAsync(deg, 0, (size_t)NN * 4, stream);

    tnorm_lsep_k<<<1, 64, 0, stream>>>(tilde_phi, tnorm, lsep_ptr);
    wprep_k<<<(116736 + 255) / 256, 256, 0, stream>>>(W, W1, W2, W_phi, W_t, W1_bf,
                                                      W2_bf, Wphi_t, lfocus_ptr);

    const int MB128 = (NN + 127) / 128;   // 391
    const int MB64  = (NN + 63) / 64;     // 782

    // hid = relu(e_l @ W1^T + b1) -> bf16 (A f32 read once)
    hgemm_k<128, true, false><<<MB64, 256, 0, stream>>>(e_l, W1_bf, b1, hid_bf);
    // phi = e_l @ W_phi (padded to 16 cols)
    mgemm_k<128, 16, 1, 2, 1, false, false, true, false, false>
        <<<dim3(MB128, 1), 256, 0, stream>>>(e_l, Wphi_t, nullptr, phi, NN, 16,
                                             nullptr, nullptr);
    // delta' = hid @ W2^T + b2 + tnorm -> f32; l_focus on raw delta
    mgemm_k<256, 64, 1, 2, 4, false, false, false, true, true>
        <<<dim3(MB128, 1), 256, 0, stream>>>(hid_bf, W2_bf, b2, deltap, NN, 64,
                                             lfocus_ptr, tnorm);
    // h = h_l @ W -> fp8 e4m3, [ch][k]-interleaved (A f32 read once)
    hgemm_k<256, false, true><<<MB64, 256, 0, stream>>>(h_l, W_t, nullptr, h8);

    // CSR build
    degree_k<<<3125, 256, 0, stream>>>(dst, deg);
    scan_partial_k<<<SCAN_NB, 256, 0, stream>>>(deg, bsum);
    scan_bsum_k<<<1, 256, 0, stream>>>(bsum);
    scan_scatter_k<<<SCAN_NB, 256, 0, stream>>>(deg, bsum, offs, cursor);
    scatter_src_k<<<3125, 256, 0, stream>>>(src, dst, cursor, csr_src, csr_dst);

    // edge weights (thread-per-slot, CSR-ordered)
    edge_w_k<<<3125, 256, 0, stream>>>(csr_src, csr_dst, phi, deltap, (float4*)csr_w);

    // per-dst single-pass softmax + aggregation + normalize
    aggregate_k<<<12500, 256, 0, stream>>>(offs, csr_src, (const float4*)csr_w,
                                           (const unsigned int*)h8, bias, out);
}

// Round 9
// 311.342 us; speedup vs baseline: 1.6694x; 1.0027x over previous
//
#include <hip/hip_runtime.h>
#include <math.h>

#define NN 50000
#define EE 800000
#define RAWD 128
#define HIDD 256
#define OUTD 64
#define KK 4
#define PHID 16

// LDS row stride for BK=32 tiles: 32 + 8 pad -> 80 B rows, banks spread 8-way,
// 16B alignment preserved. (row*20 + slot*4) % 32 covers 8 distinct banks.
#define LSTR 40

typedef __attribute__((ext_vector_type(8))) short short8;
typedef __attribute__((ext_vector_type(4))) float f32x4;

__device__ inline float b2f(unsigned short u) {
    union { unsigned i; float f; } v; v.i = ((unsigned)u) << 16; return v.f;
}
__device__ inline unsigned short f2b(float f) {
    unsigned u = __float_as_uint(f);
    unsigned r = (u + 0x7FFFu + ((u >> 16) & 1u)) >> 16;   // RNE
    return (unsigned short)r;
}
__device__ inline unsigned char f2fp8(float v) {
    return (unsigned char)(__builtin_amdgcn_cvt_pk_fp8_f32(v, v, 0, false) & 0xFF);
}

// ---------------------------------------------------------------------------
// weight prep: W_t (perm: row cp=ch*4+k), W1, W2, Wphi_t (+pad), zero l_focus
// ---------------------------------------------------------------------------
__global__ void wprep_k(const float* __restrict__ W, const float* __restrict__ W1,
                        const float* __restrict__ W2, const float* __restrict__ W_phi,
                        unsigned short* __restrict__ W_t, unsigned short* __restrict__ W1_bf,
                        unsigned short* __restrict__ W2_bf, unsigned short* __restrict__ Wphi_t,
                        float* __restrict__ lfocus_zero) {
    int i = blockIdx.x * 256 + threadIdx.x;
    if (i == 0) *lfocus_zero = 0.f;
    if (i < 65536) {
        int cp = i >> 8, r = i & 255;
        int ch = cp >> 2, k = cp & 3;
        W_t[i] = f2b(W[(size_t)r * 256 + (k << 6) + ch]);
    } else if (i < 65536 + 32768) {
        int j = i - 65536;
        W1_bf[j] = f2b(W1[j]);
    } else if (i < 65536 + 32768 + 16384) {
        int j = i - 98304;
        W2_bf[j] = f2b(W2[j]);
    } else if (i < 65536 + 32768 + 16384 + 2048) {
        int j = i - 114688;
        int cp = j >> 7, r = j & 127;
        Wphi_t[j] = (cp < 15) ? f2b(W_phi[(size_t)r * 15 + cp]) : (unsigned short)0;
    }
}

// ---------------------------------------------------------------------------
// tilde_norm + l_sep
// ---------------------------------------------------------------------------
__global__ void tnorm_lsep_k(const float* __restrict__ tilde_phi,
                             float* __restrict__ tnorm,
                             float* __restrict__ lsep_out) {
    __shared__ float tn[KK][PHID];
    int t = threadIdx.x;
    if (t < KK * PHID) {
        float v = tilde_phi[t];
        float sq = v * v;
        #pragma unroll
        for (int s = 8; s; s >>= 1) sq += __shfl_xor(sq, s, 16);
        float tnv = v / sqrtf(sq);
        tn[t >> 4][t & 15] = tnv;
        tnorm[t] = tnv;
    }
    __syncthreads();
    if (t == 0) {
        float tot = 0.f;
        for (int i = 0; i < KK; ++i)
            for (int j = 0; j < KK; ++j) {
                float s2 = 0.f;
                for (int p = 0; p < PHID; ++p) {
                    float df = tn[i][p] - tn[j][p];
                    s2 += df * df;
                }
                tot += s2;
            }
        lsep_out[0] = tot / (float)KK;
    }
}

// ---------------------------------------------------------------------------
// hgemm: BM=64, BN=256 (single col pass, A f32 read ONCE), 256 thr / 4 waves.
// Padded LDS rows (LSTR=40) -> conflict-free fragment reads.
// ---------------------------------------------------------------------------
template <int KD, bool RELU, bool OUT_FP8>
__global__ __launch_bounds__(256) void hgemm_k(const float* __restrict__ A,
                                               const unsigned short* __restrict__ Bt,
                                               const float* __restrict__ bias_vec,
                                               void* __restrict__ Cout) {
    const int BM = 64, BK = 32;
    __shared__ __align__(16) unsigned short As[BM * LSTR];
    __shared__ __align__(16) unsigned short Bs[256 * LSTR];
    const int tid = threadIdx.x;
    const int w = tid >> 6, l = tid & 63;
    const int row0 = blockIdx.x * BM;
    const int wn0 = w * 64;
    const int l15 = l & 15, l4 = l >> 4;

    const int ar = tid >> 2, ak = (tid & 3) * 8;
    int arow = row0 + ar; if (arow >= NN) arow = NN - 1;

    float4 fa0, fa1;
    uint4 breg[4];
    f32x4 acc[4][4];
    #pragma unroll
    for (int m = 0; m < 4; ++m)
        #pragma unroll
        for (int n = 0; n < 4; ++n)
            acc[m][n] = (f32x4){0.f, 0.f, 0.f, 0.f};

    auto loadT = [&](int k0) {
        const float* Af = A + (size_t)arow * KD + k0 + ak;
        fa0 = *(const float4*)Af;
        fa1 = *(const float4*)(Af + 4);
        #pragma unroll
        for (int i = 0; i < 4; ++i) {
            int c = tid + i * 256;
            breg[i] = *(const uint4*)&Bt[(size_t)(c >> 2) * KD + k0 + (c & 3) * 8];
        }
    };
    auto writeT = [&]() {
        unsigned u0 = f2b(fa0.x) | ((unsigned)f2b(fa0.y) << 16);
        unsigned u1 = f2b(fa0.z) | ((unsigned)f2b(fa0.w) << 16);
        unsigned u2 = f2b(fa1.x) | ((unsigned)f2b(fa1.y) << 16);
        unsigned u3 = f2b(fa1.z) | ((unsigned)f2b(fa1.w) << 16);
        *(uint4*)&As[ar * LSTR + ak] = make_uint4(u0, u1, u2, u3);
        #pragma unroll
        for (int i = 0; i < 4; ++i) {
            int c = tid + i * 256;
            *(uint4*)&Bs[(c >> 2) * LSTR + (c & 3) * 8] = breg[i];
        }
    };

    loadT(0);
    const int NT = KD / BK;
    for (int t = 0; t < NT; ++t) {
        __syncthreads();
        writeT();
        __syncthreads();
        if (t + 1 < NT) loadT((t + 1) * BK);
        short8 af[4], bfr[4];
        #pragma unroll
        for (int m = 0; m < 4; ++m)
            af[m] = *(const short8*)&As[(m * 16 + l15) * LSTR + l4 * 8];
        #pragma unroll
        for (int n = 0; n < 4; ++n)
            bfr[n] = *(const short8*)&Bs[(wn0 + n * 16 + l15) * LSTR + l4 * 8];
        #pragma unroll
        for (int m = 0; m < 4; ++m)
            #pragma unroll
            for (int n = 0; n < 4; ++n)
                acc[m][n] = __builtin_amdgcn_mfma_f32_16x16x32_bf16(af[m], bfr[n], acc[m][n], 0, 0, 0);
    }

    #pragma unroll
    for (int m = 0; m < 4; ++m) {
        #pragma unroll
        for (int n = 0; n < 4; ++n) {
            int gc = wn0 + n * 16 + l15;
            float bv = bias_vec ? bias_vec[gc] : 0.f;
            #pragma unroll
            for (int r = 0; r < 4; ++r) {
                int gr = row0 + m * 16 + l4 * 4 + r;
                if (gr >= NN) continue;
                float v = acc[m][n][r] + bv;
                if (RELU) v = fmaxf(v, 0.f);
                if (OUT_FP8)
                    ((unsigned char*)Cout)[(size_t)gr * 256 + gc] = f2fp8(v);
                else
                    ((unsigned short*)Cout)[(size_t)gr * 256 + gc] = f2b(v);
            }
        }
    }
}

// ---------------------------------------------------------------------------
// mgemm (BM=128): used for phi (BN=16) and delta (BN=64, TNADJ+LFOCUS).
// Padded LDS rows (LSTR).
// ---------------------------------------------------------------------------
template <int KD, int BN, int WN_WAVES, int AM, int AN, bool RELU, bool OUT_BF16,
          bool AF32, bool LFOCUS, bool TNADJ>
__global__ __launch_bounds__(256) void mgemm_k(const void* __restrict__ A,
                                               const unsigned short* __restrict__ Bt,
                                               const float* __restrict__ bias_vec,
                                               void* __restrict__ Cout,
                                               int nrows, int ldc,
                                               float* __restrict__ lfocus_acc,
                                               const float* __restrict__ tn_vec) {
    const int BM = 128, BK = 32;
    __shared__ __align__(16) unsigned short As[BM * LSTR];
    __shared__ __align__(16) unsigned short Bs[BN * LSTR];
    const int tid = threadIdx.x;
    const int w = tid >> 6, l = tid & 63;
    const int row0 = blockIdx.x * BM;
    const int col0 = blockIdx.y * BN;
    const int wr = w / WN_WAVES, wc = w % WN_WAVES;
    const int wm0 = wr * (AM * 16), wn0 = wc * (AN * 16);
    const int l15 = l & 15, l4 = l >> 4;

    const int A_PER = (BM * 4) / 256;          // 2
    const int B_CHUNKS = BN * 4;

    uint4 areg[A_PER];
    uint4 breg[(B_CHUNKS + 255) / 256];

    f32x4 acc[AM][AN];
    #pragma unroll
    for (int m = 0; m < AM; ++m)
        #pragma unroll
        for (int n = 0; n < AN; ++n)
            acc[m][n] = (f32x4){0.f, 0.f, 0.f, 0.f};

    auto loadTiles = [&](int k0) {
        #pragma unroll
        for (int i = 0; i < A_PER; ++i) {
            int idx = i * 256 + tid;
            int r = idx >> 2, c = idx & 3;
            int gr = row0 + r; if (gr >= nrows) gr = nrows - 1;
            if (AF32) {
                const float* Af = (const float*)A + (size_t)gr * KD + k0 + c * 8;
                float4 f0 = *(const float4*)Af;
                float4 f1 = *(const float4*)(Af + 4);
                unsigned u0 = f2b(f0.x) | ((unsigned)f2b(f0.y) << 16);
                unsigned u1 = f2b(f0.z) | ((unsigned)f2b(f0.w) << 16);
                unsigned u2 = f2b(f1.x) | ((unsigned)f2b(f1.y) << 16);
                unsigned u3 = f2b(f1.z) | ((unsigned)f2b(f1.w) << 16);
                areg[i] = make_uint4(u0, u1, u2, u3);
            } else {
                areg[i] = *(const uint4*)&((const unsigned short*)A)[(size_t)gr * KD + k0 + c * 8];
            }
        }
        if (B_CHUNKS >= 256) {
            #pragma unroll
            for (int i = 0; i < B_CHUNKS / 256; ++i) {
                int idx = i * 256 + tid;
                int r = idx >> 2, c = idx & 3;
                breg[i] = *(const uint4*)&Bt[(size_t)(col0 + r) * KD + k0 + c * 8];
            }
        } else if (tid < B_CHUNKS) {
            int r = tid >> 2, c = tid & 3;
            breg[0] = *(const uint4*)&Bt[(size_t)(col0 + r) * KD + k0 + c * 8];
        }
    };
    auto writeTiles = [&]() {
        #pragma unroll
        for (int i = 0; i < A_PER; ++i) {
            int idx = i * 256 + tid;
            *(uint4*)&As[(idx >> 2) * LSTR + (idx & 3) * 8] = areg[i];
        }
        if (B_CHUNKS >= 256) {
            #pragma unroll
            for (int i = 0; i < B_CHUNKS / 256; ++i) {
                int idx = i * 256 + tid;
                *(uint4*)&Bs[(idx >> 2) * LSTR + (idx & 3) * 8] = breg[i];
            }
        } else if (tid < B_CHUNKS) {
            *(uint4*)&Bs[(tid >> 2) * LSTR + (tid & 3) * 8] = breg[0];
        }
    };

    loadTiles(0);
    const int NT = KD / BK;
    for (int t = 0; t < NT; ++t) {
        __syncthreads();
        writeTiles();
        __syncthreads();
        if (t + 1 < NT) loadTiles((t + 1) * BK);
        short8 af[AM], bfr[AN];
        #pragma unroll
        for (int m = 0; m < AM; ++m)
            af[m] = *(const short8*)&As[(wm0 + m * 16 + l15) * LSTR + l4 * 8];
        #pragma unroll
        for (int n = 0; n < AN; ++n)
            bfr[n] = *(const short8*)&Bs[(wn0 + n * 16 + l15) * LSTR + l4 * 8];
        #pragma unroll
        for (int m = 0; m < AM; ++m)
            #pragma unroll
            for (int n = 0; n < AN; ++n)
                acc[m][n] = __builtin_amdgcn_mfma_f32_16x16x32_bf16(af[m], bfr[n], acc[m][n], 0, 0, 0);
    }

    float lf = 0.f;
    #pragma unroll
    for (int m = 0; m < AM; ++m) {
        #pragma unroll
        for (int n = 0; n < AN; ++n) {
            int gc = col0 + wn0 + n * 16 + l15;
            float bv = bias_vec ? bias_vec[gc] : 0.f;
            float tv = TNADJ ? tn_vec[gc] : 0.f;
            #pragma unroll
            for (int r = 0; r < 4; ++r) {
                int gr = row0 + wm0 + m * 16 + l4 * 4 + r;
                if (gr >= nrows) continue;
                float v = acc[m][n][r] + bv;
                if (RELU) v = fmaxf(v, 0.f);
                if (LFOCUS) lf += v * v;
                if (TNADJ) v += tv;
                if (OUT_BF16)
                    ((unsigned short*)Cout)[(size_t)gr * ldc + gc] = f2b(v);
                else
                    ((float*)Cout)[(size_t)gr * ldc + gc] = v;
            }
        }
    }
    if (LFOCUS) {
        #pragma unroll
        for (int s = 32; s; s >>= 1) lf += __shfl_xor(lf, s);
        if ((tid & 63) == 0)
            atomicAdd(lfocus_acc, lf * (1.f / ((float)NN * KK)));
    }
}

// ---------------------------------------------------------------------------
__global__ void degree_k(const int* __restrict__ dst, int* __restrict__ deg) {
    int e = blockIdx.x * 256 + threadIdx.x;
    if (e < EE) atomicAdd(&deg[dst[e]], 1);
}

#define SCAN_NB ((NN + 255) / 256)   // 196

__global__ __launch_bounds__(256) void scan_partial_k(const int* __restrict__ deg,
                                                      int* __restrict__ bsum) {
    __shared__ int ws_[4];
    int i = blockIdx.x * 256 + threadIdx.x;
    int v = (i < NN) ? deg[i] : 0;
    int x = v;
    #pragma unroll
    for (int s = 32; s; s >>= 1) x += __shfl_xor(x, s);
    if ((threadIdx.x & 63) == 0) ws_[threadIdx.x >> 6] = x;
    __syncthreads();
    if (threadIdx.x == 0) bsum[blockIdx.x] = ws_[0] + ws_[1] + ws_[2] + ws_[3];
}

__global__ __launch_bounds__(256) void scan_bsum_k(int* __restrict__ bsum) {
    __shared__ int sd[256];
    int t = threadIdx.x;
    int v = (t < SCAN_NB) ? bsum[t] : 0;
    sd[t] = v;
    __syncthreads();
    for (int s = 1; s < 256; s <<= 1) {
        int u = (t >= s) ? sd[t - s] : 0;
        __syncthreads();
        sd[t] += u;
        __syncthreads();
    }
    if (t < SCAN_NB) bsum[t] = sd[t] - v;   // exclusive
}

__global__ __launch_bounds__(256) void scan_scatter_k(const int* __restrict__ deg,
                                                      const int* __restrict__ bsum,
                                                      int* __restrict__ offs,
                                                      int* __restrict__ cursor) {
    __shared__ int wexc[4];
    int i = blockIdx.x * 256 + threadIdx.x;
    int lane = threadIdx.x & 63, wid = threadIdx.x >> 6;
    int v = (i < NN) ? deg[i] : 0;
    int x = v;
    #pragma unroll
    for (int d = 1; d < 64; d <<= 1) { int u = __shfl_up(x, d); if (lane >= d) x += u; }
    if (lane == 63) wexc[wid] = x;
    __syncthreads();
    if (threadIdx.x == 0) {
        int a = wexc[0], b = wexc[1], c = wexc[2];
        wexc[0] = 0; wexc[1] = a; wexc[2] = a + b; wexc[3] = a + b + c;
    }
    __syncthreads();
    int excl = (x - v) + wexc[wid] + bsum[blockIdx.x];
    if (i < NN) {
        cursor[i] = excl;
        offs[i + 1] = excl + v;
        if (i == 0) offs[0] = 0;
    }
}

__global__ void scatter_src_k(const int* __restrict__ src, const int* __restrict__ dst,
                              int* __restrict__ cursor, int* __restrict__ csr_src,
                              int* __restrict__ csr_dst) {
    int e = blockIdx.x * 256 + threadIdx.x;
    if (e >= EE) return;
    int d = dst[e];
    int pos = atomicAdd(&cursor[d], 1);
    csr_src[pos] = src[e];
    csr_dst[pos] = d;
}

// ---------------------------------------------------------------------------
// edge weights, thread per CSR slot. delta' already includes tnorm.
// ---------------------------------------------------------------------------
__global__ __launch_bounds__(256) void edge_w_k(const int* __restrict__ csr_src,
                                                const int* __restrict__ csr_dst,
                                                const float* __restrict__ phi,
                                                const float* __restrict__ deltap,
                                                float4* __restrict__ csr_w) {
    int e = blockIdx.x * 256 + threadIdx.x;
    if (e >= EE) return;
    int s = csr_src[e], d = csr_dst[e];
    const float4* ps4 = (const float4*)(phi + (size_t)s * 16);
    const float4* pd4 = (const float4*)(phi + (size_t)d * 16);
    float dv[16];
    float nrm2 = 0.f;
    #pragma unroll
    for (int q = 0; q < 4; ++q) {
        float4 a = ps4[q], b = pd4[q];
        dv[q * 4 + 0] = a.x - b.x;
        dv[q * 4 + 1] = a.y - b.y;
        dv[q * 4 + 2] = a.z - b.z;
        dv[q * 4 + 3] = a.w - b.w;
    }
    #pragma unroll
    for (int p = 0; p < 15; ++p) nrm2 += dv[p] * dv[p];
    float z = (nrm2 == 0.f) ? 1.f : 0.f;
    dv[15] = z;
    nrm2 += z;
    float inv = 1.f / fmaxf(sqrtf(nrm2), 1e-8f);
    const float* dl = deltap + (size_t)d * 64;
    float res[4];
    #pragma unroll
    for (int k = 0; k < 4; ++k) {
        const float4* dk = (const float4*)(dl + k * 16);
        float sacc = 0.f;
        #pragma unroll
        for (int q = 0; q < 4; ++q) {
            float4 tv = dk[q];
            sacc += dv[q * 4 + 0] * tv.x;
            sacc += dv[q * 4 + 1] * tv.y;
            sacc += dv[q * 4 + 2] * tv.z;
            sacc += dv[q * 4 + 3] * tv.w;
        }
        res[k] = sacc * inv;
    }
    csr_w[e] = make_float4(__expf(res[0]), __expf(res[1]),
                           __expf(res[2]), __expf(res[3]));
}

// ---------------------------------------------------------------------------
// per-dst single-pass aggregation. Wave per node, lane = channel.
// h is fp8 [node][ch][k]: one uint (4 fp8) gather per lane per edge.
// ---------------------------------------------------------------------------
__global__ __launch_bounds__(256) void aggregate_k(const int* __restrict__ offs,
                                                   const int* __restrict__ csr_src,
                                                   const float4* __restrict__ csr_w,
                                                   const unsigned int* __restrict__ h8,
                                                   const float* __restrict__ bias,
                                                   float* __restrict__ out) {
    int wave = threadIdx.x >> 6;
    int lane = threadIdx.x & 63;
    int n = blockIdx.x * 4 + wave;
    if (n >= NN) return;
    int beg = offs[n], end = offs[n + 1];

    float a0 = 0.f, a1 = 0.f, a2 = 0.f, a3 = 0.f;
    float d0 = 0.f, d1 = 0.f, d2 = 0.f, d3 = 0.f;
    int p = beg;
    for (; p + 3 < end; p += 4) {
        float4 w0 = csr_w[p], w1 = csr_w[p + 1], w2 = csr_w[p + 2], w3 = csr_w[p + 3];
        int s0 = csr_src[p], s1 = csr_src[p + 1], s2 = csr_src[p + 2], s3 = csr_src[p + 3];
        unsigned hv0 = h8[(size_t)s0 * 64 + lane];
        unsigned hv1 = h8[(size_t)s1 * 64 + lane];
        unsigned hv2 = h8[(size_t)s2 * 64 + lane];
        unsigned hv3 = h8[(size_t)s3 * 64 + lane];
        d0 += (w0.x + w1.x) + (w2.x + w3.x);
        d1 += (w0.y + w1.y) + (w2.y + w3.y);
        d2 += (w0.z + w1.z) + (w2.z + w3.z);
        d3 += (w0.w + w1.w) + (w2.w + w3.w);
        a0 += w0.x * __builtin_amdgcn_cvt_f32_fp8(hv0, 0) + w1.x * __builtin_amdgcn_cvt_f32_fp8(hv1, 0)
            + w2.x * __builtin_amdgcn_cvt_f32_fp8(hv2, 0) + w3.x * __builtin_amdgcn_cvt_f32_fp8(hv3, 0);
        a1 += w0.y * __builtin_amdgcn_cvt_f32_fp8(hv0, 1) + w1.y * __builtin_amdgcn_cvt_f32_fp8(hv1, 1)
            + w2.y * __builtin_amdgcn_cvt_f32_fp8(hv2, 1) + w3.y * __builtin_amdgcn_cvt_f32_fp8(hv3, 1);
        a2 += w0.z * __builtin_amdgcn_cvt_f32_fp8(hv0, 2) + w1.z * __builtin_amdgcn_cvt_f32_fp8(hv1, 2)
            + w2.z * __builtin_amdgcn_cvt_f32_fp8(hv2, 2) + w3.z * __builtin_amdgcn_cvt_f32_fp8(hv3, 2);
        a3 += w0.w * __builtin_amdgcn_cvt_f32_fp8(hv0, 3) + w1.w * __builtin_amdgcn_cvt_f32_fp8(hv1, 3)
            + w2.w * __builtin_amdgcn_cvt_f32_fp8(hv2, 3) + w3.w * __builtin_amdgcn_cvt_f32_fp8(hv3, 3);
    }
    for (; p < end; ++p) {
        float4 wA = csr_w[p];
        int sA = csr_src[p];
        unsigned hv = h8[(size_t)sA * 64 + lane];
        d0 += wA.x; d1 += wA.y; d2 += wA.z; d3 += wA.w;
        a0 += wA.x * __builtin_amdgcn_cvt_f32_fp8(hv, 0);
        a1 += wA.y * __builtin_amdgcn_cvt_f32_fp8(hv, 1);
        a2 += wA.z * __builtin_amdgcn_cvt_f32_fp8(hv, 2);
        a3 += wA.w * __builtin_amdgcn_cvt_f32_fp8(hv, 3);
    }
    float v = (d0 > 0.f ? a0 / d0 : 0.f) + (d1 > 0.f ? a1 / d1 : 0.f) +
              (d2 > 0.f ? a2 / d2 : 0.f) + (d3 > 0.f ? a3 / d3 : 0.f) + bias[lane];
    float nr = v * v;
    #pragma unroll
    for (int s = 32; s; s >>= 1) nr += __shfl_xor(nr, s);
    float invn = 1.f / fmaxf(sqrtf(nr), 1e-8f);
    out[(size_t)n * 64 + lane] = v * invn;
}

// ---------------------------------------------------------------------------
extern "C" void kernel_launch(void* const* d_in, const int* in_sizes, int n_in,
                              void* d_out, int out_size, void* d_ws, size_t ws_size,
                              hipStream_t stream) {
    const float* h_l       = (const float*)d_in[0];
    const float* e_l       = (const float*)d_in[1];
    const int*   src       = (const int*)d_in[2];
    const int*   dst       = (const int*)d_in[3];
    const float* W_phi     = (const float*)d_in[4];
    const float* W1        = (const float*)d_in[5];
    const float* b1        = (const float*)d_in[6];
    const float* W2        = (const float*)d_in[7];
    const float* b2        = (const float*)d_in[8];
    const float* tilde_phi = (const float*)d_in[9];
    const float* W         = (const float*)d_in[10];
    const float* bias      = (const float*)d_in[11];
    float* out = (float*)d_out;
    float* lsep_ptr   = out + (size_t)NN * OUTD;
    float* lfocus_ptr = out + (size_t)NN * OUTD + 1;

    char* ws = (char*)d_ws;
    size_t off = 0;
    auto alloc = [&](size_t bytes) -> char* {
        char* p = ws + off;
        off += (bytes + 255) & ~(size_t)255;
        return p;
    };
    float*          phi     = (float*)alloc((size_t)NN * 16 * 4);
    float*          deltap  = (float*)alloc((size_t)NN * 64 * 4);
    unsigned char*  h8      = (unsigned char*)alloc((size_t)NN * 256);
    unsigned short* hid_bf  = (unsigned short*)alloc((size_t)NN * 256 * 2);
    int*            csr_src = (int*)alloc((size_t)EE * 4);
    int*            csr_dst = (int*)alloc((size_t)EE * 4);
    float*          csr_w   = (float*)alloc((size_t)EE * 4 * 4);
    int*            deg     = (int*)alloc((size_t)NN * 4);
    int*            offs    = (int*)alloc((size_t)(NN + 1) * 4);
    int*            cursor  = (int*)alloc((size_t)NN * 4);
    int*            bsum    = (int*)alloc((size_t)SCAN_NB * 4);
    unsigned short* W_t     = (unsigned short*)alloc(256 * 256 * 2);
    unsigned short* W1_bf   = (unsigned short*)alloc(256 * 128 * 2);
    unsigned short* W2_bf   = (unsigned short*)alloc(64 * 256 * 2);
    unsigned short* Wphi_t  = (unsigned short*)alloc(16 * 128 * 2);
    float*          tnorm   = (float*)alloc(64 * 4);

    hipMemsetAsync(deg, 0, (size_t)NN * 4, stream);

    tnorm_lsep_k<<<1, 64, 0, stream>>>(tilde_phi, tnorm, lsep_ptr);
    wprep_k<<<(116736 + 255) / 256, 256, 0, stream>>>(W, W1, W2, W_phi, W_t, W1_bf,
                                                      W2_bf, Wphi_t, lfocus_ptr);

    const int MB128 = (NN + 127) / 128;   // 391
    const int MB64  = (NN + 63) / 64;     // 782

    // hid = relu(e_l @ W1^T + b1) -> bf16 (A f32 read once)
    hgemm_k<128, true, false><<<MB64, 256, 0, stream>>>(e_l, W1_bf, b1, hid_bf);
    // phi = e_l @ W_phi (padded to 16 cols)
    mgemm_k<128, 16, 1, 2, 1, false, false, true, false, false>
        <<<dim3(MB128, 1), 256, 0, stream>>>(e_l, Wphi_t, nullptr, phi, NN, 16,
                                             nullptr, nullptr);
    // delta' = hid @ W2^T + b2 + tnorm -> f32; l_focus on raw delta
    mgemm_k<256, 64, 1, 2, 4, false, false, false, true, true>
        <<<dim3(MB128, 1), 256, 0, stream>>>(hid_bf, W2_bf, b2, deltap, NN, 64,
                                             lfocus_ptr, tnorm);
    // h = h_l @ W -> fp8 e4m3, [ch][k]-interleaved (A f32 read once)
    hgemm_k<256, false, true><<<MB64, 256, 0, stream>>>(h_l, W_t, nullptr, h8);

    // CSR build
    degree_k<<<3125, 256, 0, stream>>>(dst, deg);
    scan_partial_k<<<SCAN_NB, 256, 0, stream>>>(deg, bsum);
    scan_bsum_k<<<1, 256, 0, stream>>>(bsum);
    scan_scatter_k<<<SCAN_NB, 256, 0, stream>>>(deg, bsum, offs, cursor);
    scatter_src_k<<<3125, 256, 0, stream>>>(src, dst, cursor, csr_src, csr_dst);

    // edge weights (thread-per-slot, CSR-ordered)
    edge_w_k<<<3125, 256, 0, stream>>>(csr_src, csr_dst, phi, deltap, (float4*)csr_w);

    // per-dst single-pass softmax + aggregation + normalize
    aggregate_k<<<12500, 256, 0, stream>>>(offs, csr_src, (const float4*)csr_w,
                                           (const unsigned int*)h8, bias, out);
}